// Round 2
// baseline (4036.448 us; speedup 1.0000x reference)
//
#include <hip/hip_runtime.h>
#include <hip/hip_bf16.h>
#include <hip/hip_fp16.h>
#include <cstdint>

// ---------------------------------------------------------------------------
// LinearAttention (random-feature cos kernel + softmax attention), MI355X.
// out = softmax(cos(q@Wq@Wr + br) @ cos(v@Wk@Wr + br)^T) @ (v@Wv + bv)
// B=4, S=4096, D=U=F=1024.  All heavy math in fp16 MFMA with fp32 accum.
// Workspace plan (aliased, ~168.2 MB total):
//   bufA: q16 -> Khat          bufB: v16 -> probs(1 batch)
//   bufC: Qhat                 bufD: VT
// ---------------------------------------------------------------------------

typedef _Float16 f16;
typedef _Float16 f16x8 __attribute__((ext_vector_type(8)));
typedef _Float16 f16x4 __attribute__((ext_vector_type(4)));
typedef float f32x4 __attribute__((ext_vector_type(4)));

typedef __attribute__((address_space(1))) unsigned int uas1;
typedef __attribute__((address_space(3))) unsigned int uas3;

#define NB 4
#define SEQ 4096
#define DIM 1024

// async 16B/lane global->LDS. LDS dest must be wave-uniform base (+lane*16).
__device__ __forceinline__ void async_copy16(void* lds, const void* g) {
  __builtin_amdgcn_global_load_lds((uas1*)(uintptr_t)g, (uas3*)(uintptr_t)lds,
                                   16, 0, 0);
}

// ----------------------------- small kernels ------------------------------

__global__ __launch_bounds__(256) void f2h(const float* __restrict__ in,
                                           f16* __restrict__ out, int n4) {
  int i = blockIdx.x * 256 + threadIdx.x;
  if (i < n4) {
    float4 v = ((const float4*)in)[i];
    f16x4 h = {(f16)v.x, (f16)v.y, (f16)v.z, (f16)v.w};
    ((f16x4*)out)[i] = h;
  }
}

__global__ __launch_bounds__(256) void f2h_split(const float* __restrict__ in,
                                                 f16* __restrict__ hi,
                                                 f16* __restrict__ lo, int n4) {
  int i = blockIdx.x * 256 + threadIdx.x;
  if (i < n4) {
    float4 v = ((const float4*)in)[i];
    f16 h0 = (f16)v.x, h1 = (f16)v.y, h2 = (f16)v.z, h3 = (f16)v.w;
    f16x4 hv = {h0, h1, h2, h3};
    f16x4 lv = {(f16)(v.x - (float)h0), (f16)(v.y - (float)h1),
                (f16)(v.z - (float)h2), (f16)(v.w - (float)h3)};
    ((f16x4*)hi)[i] = hv;
    ((f16x4*)lo)[i] = lv;
  }
}

__global__ void tr_h(const f16* __restrict__ in, f16* __restrict__ out, int R,
                     int C) {
  __shared__ f16 tile[32][33];
  int c0 = blockIdx.x * 32, r0 = blockIdx.y * 32;
  tile[threadIdx.y][threadIdx.x] =
      in[(long)(r0 + threadIdx.y) * C + c0 + threadIdx.x];
  __syncthreads();
  out[(long)(c0 + threadIdx.y) * R + r0 + threadIdx.x] =
      tile[threadIdx.x][threadIdx.y];
}

// bias_eff[f] = br[f] + sum_u bvec[u] * Wr[u][f]   (fp32 exact)
__global__ __launch_bounds__(256) void bias_fold(const float* __restrict__ br,
                                                 const float* __restrict__ bvec,
                                                 const float* __restrict__ Wr,
                                                 float* __restrict__ outb) {
  int f = blockIdx.x * 256 + threadIdx.x;
  float s = br[f];
  for (int u = 0; u < DIM; ++u) s = fmaf(bvec[u], Wr[(long)u * DIM + f], s);
  outb[f] = s;
}

__global__ __launch_bounds__(256) void stats_merge(const float* __restrict__ mp,
                                                   const float* __restrict__ lp,
                                                   float* __restrict__ mo,
                                                   float* __restrict__ li) {
  int i = blockIdx.x * 256 + threadIdx.x;  // 0..16383  (z*4096 + q)
  int z = i >> 12, q = i & 4095;
  float m0 = mp[(long)(z * 2 + 0) * SEQ + q], m1 = mp[(long)(z * 2 + 1) * SEQ + q];
  float l0 = lp[(long)(z * 2 + 0) * SEQ + q], l1 = lp[(long)(z * 2 + 1) * SEQ + q];
  float mm = fmaxf(m0, m1);
  float ll = l0 * __expf(m0 - mm) + l1 * __expf(m1 - mm);
  mo[i] = mm;
  li[i] = 1.0f / ll;
}

__global__ void sentinel(float* out) { out[0] = 12345.0f; }

// ------------------------------- main GEMM --------------------------------
// C[M,N] = epilogue( sum_passes A_p[M,K] @ B_p[N,K]^T )
// Bt stored row-major [N,K].  128x128 tile, 4 waves, 4x4 16x16x32 frags/wave.
// NPASS=1: (Ah,Bh).  NPASS=2: +(Ah,Bl).  NPASS=3: (Ah,Bh)+(Al,Bh)+(Ah,Bl).
// EPI: 0 f16  | 1 f16 cos(v+aux[col]) | 2 f16 v+aux[row] | 3 f16 exp(v-aux[row])
//      4 f32 v*aux[row] | 5 f32
template <int EPI, int NPASS>
__global__ __launch_bounds__(256) void gemm_bt(
    const f16* __restrict__ Ah, const f16* __restrict__ Al,
    const f16* __restrict__ Bh, const f16* __restrict__ Bl,
    void* __restrict__ Cv, const float* __restrict__ aux, int M, int N, int K,
    int lda, int ldb, int ldc, long sA, long sB, long sC, int sAux) {
  __shared__ __align__(16) f16 As[128 * 32];
  __shared__ __align__(16) f16 Bs[128 * 32];
  const int z = blockIdx.z;
  const int tn = blockIdx.x, tm = blockIdx.y;
  const int t = threadIdx.x, w = t >> 6, l = t & 63;
  const int l4 = l >> 4, l15 = l & 15;
  const int wm = w & 1, wn = w >> 1;
  f32x4 acc[4][4] = {};

  for (int pass = 0; pass < NPASS; ++pass) {
    const f16* Ap = Ah;
    const f16* Bp = Bh;
    if (NPASS == 3) {
      if (pass == 1) Ap = Al;
      if (pass == 2) Bp = Bl;
    } else if (NPASS == 2) {
      if (pass == 1) Bp = Bl;
    }
    const f16* Az = Ap + (long)z * sA;
    const f16* Bz = Bp + (long)z * sB;
    for (int kk = 0; kk < K; kk += 32) {
      __syncthreads();
#pragma unroll
      for (int j = 0; j < 2; ++j) {
        const int cb = w * 64 + j * 256;  // wave-uniform base chunk
        const int c = cb + l;             // this lane's 16B chunk
        async_copy16(&As[cb * 8],
                     Az + (long)(tm * 128 + (c >> 2)) * lda + kk + (c & 3) * 8);
        async_copy16(&Bs[cb * 8],
                     Bz + (long)(tn * 128 + (c >> 2)) * ldb + kk + (c & 3) * 8);
      }
      asm volatile("s_waitcnt vmcnt(0)" ::: "memory");
      __syncthreads();
      f16x8 af[4], bf[4];
#pragma unroll
      for (int i = 0; i < 4; ++i) {
        af[i] = *(const f16x8*)&As[(wm * 64 + i * 16 + l15) * 32 + l4 * 8];
        bf[i] = *(const f16x8*)&Bs[(wn * 64 + i * 16 + l15) * 32 + l4 * 8];
      }
#pragma unroll
      for (int i = 0; i < 4; ++i)
#pragma unroll
        for (int jn = 0; jn < 4; ++jn)
          acc[i][jn] = __builtin_amdgcn_mfma_f32_16x16x32_f16(af[i], bf[jn],
                                                              acc[i][jn], 0, 0, 0);
    }
  }

  const float* auxp = aux + (long)z * sAux;
#pragma unroll
  for (int i = 0; i < 4; ++i) {
    const int row0 = tm * 128 + wm * 64 + i * 16 + l4 * 4;
#pragma unroll
    for (int jn = 0; jn < 4; ++jn) {
      const int col = tn * 128 + wn * 64 + jn * 16 + l15;
#pragma unroll
      for (int r = 0; r < 4; ++r) {
        const int row = row0 + r;
        float v = acc[i][jn][r];
        if constexpr (EPI == 0) {
          ((f16*)Cv)[(long)z * sC + (long)row * ldc + col] = (f16)v;
        } else if constexpr (EPI == 1) {
          ((f16*)Cv)[(long)z * sC + (long)row * ldc + col] =
              (f16)cosf(v + auxp[col]);
        } else if constexpr (EPI == 2) {
          ((f16*)Cv)[(long)z * sC + (long)row * ldc + col] =
              (f16)(v + auxp[row]);
        } else if constexpr (EPI == 3) {
          ((f16*)Cv)[(long)z * sC + (long)row * ldc + col] =
              (f16)__expf(v - auxp[row]);
        } else if constexpr (EPI == 4) {
          ((float*)Cv)[(long)z * sC + (long)row * ldc + col] = v * auxp[row];
        } else {
          ((float*)Cv)[(long)z * sC + (long)row * ldc + col] = v;
        }
      }
    }
  }
}

// ------------------------- softmax statistics pass -------------------------
// grid (S/64, 2 key-halves, B); 256 thr. Per WG: 64 q-rows, 2048 keys.
// Online max/sum over k-tiles of 128. Writes partial m,l per (batch,half).
__global__ __launch_bounds__(256) void stats_kernel(const f16* __restrict__ Qh,
                                                    const f16* __restrict__ Kh,
                                                    float* __restrict__ m_part,
                                                    float* __restrict__ l_part) {
  __shared__ __align__(16) f16 Qs[64 * 32];
  __shared__ __align__(16) f16 Ks[128 * 32];
  __shared__ float red[2][64];
  __shared__ float mnew_s[64], mrun[64], lrun[64];
  const int z = blockIdx.z, ky = blockIdx.y, qt = blockIdx.x;
  const f16* Qb = Qh + (long)z * SEQ * DIM + (long)qt * 64 * DIM;
  const f16* Kb = Kh + (long)z * SEQ * DIM + (long)ky * 2048 * DIM;
  const int t = threadIdx.x, w = t >> 6, l = t & 63;
  const int l4 = l >> 4, l15 = l & 15;
  const int wm = w & 1, wn = w >> 1;
  if (t < 64) {
    mrun[t] = -1e30f;
    lrun[t] = 0.f;
  }
  for (int kt = 0; kt < 16; ++kt) {
    f32x4 acc[2][4] = {};
    for (int f = 0; f < DIM; f += 32) {
      __syncthreads();
      {
        const int cb = w * 64, c = cb + l;  // 256 chunks of Qs
        async_copy16(&Qs[cb * 8], Qb + (long)(c >> 2) * DIM + f + (c & 3) * 8);
      }
#pragma unroll
      for (int j = 0; j < 2; ++j) {  // 512 chunks of Ks
        const int cb = (j * 4 + w) * 64, c = cb + l;
        async_copy16(&Ks[cb * 8],
                     Kb + (long)(kt * 128 + (c >> 2)) * DIM + f + (c & 3) * 8);
      }
      asm volatile("s_waitcnt vmcnt(0)" ::: "memory");
      __syncthreads();
      f16x8 af[2], bf[4];
#pragma unroll
      for (int i = 0; i < 2; ++i)
        af[i] = *(const f16x8*)&Qs[(wm * 32 + i * 16 + l15) * 32 + l4 * 8];
#pragma unroll
      for (int i = 0; i < 4; ++i)
        bf[i] = *(const f16x8*)&Ks[(wn * 64 + i * 16 + l15) * 32 + l4 * 8];
#pragma unroll
      for (int i = 0; i < 2; ++i)
#pragma unroll
        for (int jn = 0; jn < 4; ++jn)
          acc[i][jn] = __builtin_amdgcn_mfma_f32_16x16x32_f16(af[i], bf[jn],
                                                              acc[i][jn], 0, 0, 0);
    }
    // per-row tile max  (row = wm*32 + i*16 + l4*4 + r, cols across jn & l15)
#pragma unroll
    for (int i = 0; i < 2; ++i)
#pragma unroll
      for (int r = 0; r < 4; ++r) {
        float v = fmaxf(fmaxf(acc[i][0][r], acc[i][1][r]),
                        fmaxf(acc[i][2][r], acc[i][3][r]));
        v = fmaxf(v, __shfl_xor(v, 1));
        v = fmaxf(v, __shfl_xor(v, 2));
        v = fmaxf(v, __shfl_xor(v, 4));
        v = fmaxf(v, __shfl_xor(v, 8));
        if (l15 == 0) red[wn][wm * 32 + i * 16 + l4 * 4 + r] = v;
      }
    __syncthreads();
    if (t < 64) mnew_s[t] = fmaxf(mrun[t], fmaxf(red[0][t], red[1][t]));
    __syncthreads();
#pragma unroll
    for (int i = 0; i < 2; ++i)
#pragma unroll
      for (int r = 0; r < 4; ++r) {
        const float mn = mnew_s[wm * 32 + i * 16 + l4 * 4 + r];
        float s = __expf(acc[i][0][r] - mn) + __expf(acc[i][1][r] - mn) +
                  __expf(acc[i][2][r] - mn) + __expf(acc[i][3][r] - mn);
        s += __shfl_xor(s, 1);
        s += __shfl_xor(s, 2);
        s += __shfl_xor(s, 4);
        s += __shfl_xor(s, 8);
        if (l15 == 0) red[wn][wm * 32 + i * 16 + l4 * 4 + r] = s;
      }
    __syncthreads();
    if (t < 64) {
      lrun[t] = lrun[t] * __expf(mrun[t] - mnew_s[t]) + red[0][t] + red[1][t];
      mrun[t] = mnew_s[t];
    }
    __syncthreads();
  }
  if (t < 64) {
    const long o = (long)(z * 2 + ky) * SEQ + qt * 64 + t;
    m_part[o] = mrun[t];
    l_part[o] = lrun[t];
  }
}

// --------------------------------- driver ----------------------------------

extern "C" void kernel_launch(void* const* d_in, const int* in_sizes, int n_in,
                              void* d_out, int out_size, void* d_ws,
                              size_t ws_size, hipStream_t stream) {
  const float* query = (const float*)d_in[0];
  const float* value = (const float*)d_in[1];
  const float* Wq = (const float*)d_in[2];
  const float* bq = (const float*)d_in[3];
  const float* Wk = (const float*)d_in[4];
  const float* bk = (const float*)d_in[5];
  const float* Wv = (const float*)d_in[6];
  const float* bv = (const float*)d_in[7];
  const float* Wr = (const float*)d_in[8];
  const float* br = (const float*)d_in[9];
  float* out = (float*)d_out;

  // ws budget check: total below is 168,173,568 bytes (+ padding slack).
  if (ws_size < 169000000ull) {
    sentinel<<<1, 1, 0, stream>>>(out);
    return;
  }

  char* p = (char*)d_ws;
  auto alloc = [&](size_t bytes) {
    char* r = p;
    p += (bytes + 255) & ~(size_t)255;
    return r;
  };
  const size_t QV = 16777216ull;  // B*S*D elements
  const size_t WW = 1048576ull;   // 1024*1024 elements
  char* bufA = alloc(QV * 2);  // q16 -> Khat
  char* bufB = alloc(QV * 2);  // v16 -> probs (one batch: 4096*4096*2 = 32MB)
  char* bufC = alloc(QV * 2);  // Qhat
  char* bufD = alloc(QV * 2);  // VT
  f16* q16 = (f16*)bufA;
  f16* Khat = (f16*)bufA;
  f16* v16 = (f16*)bufB;
  f16* probs = (f16*)bufB;
  f16* Qhat = (f16*)bufC;
  f16* VT = (f16*)bufD;
  f16* Wq_h = (f16*)alloc(WW * 2);
  f16* Wq_l = (f16*)alloc(WW * 2);
  f16* Wk_h = (f16*)alloc(WW * 2);
  f16* Wk_l = (f16*)alloc(WW * 2);
  f16* Wr_h = (f16*)alloc(WW * 2);
  f16* Wr_l = (f16*)alloc(WW * 2);
  f16* Wv16 = (f16*)alloc(WW * 2);
  f16* WrT_h = (f16*)alloc(WW * 2);
  f16* WrT_l = (f16*)alloc(WW * 2);
  f16* WvT = (f16*)alloc(WW * 2);
  float* Wtmp32 = (float*)alloc(WW * 4);
  f16* WqrT_h = (f16*)alloc(WW * 2);
  f16* WqrT_l = (f16*)alloc(WW * 2);
  f16* WkrT_h = (f16*)alloc(WW * 2);
  f16* WkrT_l = (f16*)alloc(WW * 2);
  float* brq = (float*)alloc(1024 * 4);
  float* brk = (float*)alloc(1024 * 4);
  float* mpart = (float*)alloc(8 * 4096 * 4);
  float* lpart = (float*)alloc(8 * 4096 * 4);
  float* marr = (float*)alloc(16384 * 4);
  float* linv = (float*)alloc(16384 * 4);

  // fp32 -> fp16 conversions (split for W matrices feeding Wqr/Wkr)
  f2h<<<16384, 256, 0, stream>>>(query, q16, 4194304);
  f2h<<<16384, 256, 0, stream>>>(value, v16, 4194304);
  f2h_split<<<1024, 256, 0, stream>>>(Wq, Wq_h, Wq_l, 262144);
  f2h_split<<<1024, 256, 0, stream>>>(Wk, Wk_h, Wk_l, 262144);
  f2h_split<<<1024, 256, 0, stream>>>(Wr, Wr_h, Wr_l, 262144);
  f2h<<<1024, 256, 0, stream>>>(Wv, Wv16, 262144);
  tr_h<<<dim3(32, 32), dim3(32, 32), 0, stream>>>(Wr_h, WrT_h, 1024, 1024);
  tr_h<<<dim3(32, 32), dim3(32, 32), 0, stream>>>(Wr_l, WrT_l, 1024, 1024);
  tr_h<<<dim3(32, 32), dim3(32, 32), 0, stream>>>(Wv16, WvT, 1024, 1024);
  bias_fold<<<4, 256, 0, stream>>>(br, bq, Wr, brq);
  bias_fold<<<4, 256, 0, stream>>>(br, bk, Wr, brk);

  // WqrT = Wr^T @ Wq^T in ~fp32 (3-pass split), then split to fp16 hi/lo
  gemm_bt<5, 3><<<dim3(8, 8, 1), 256, 0, stream>>>(
      WrT_h, WrT_l, Wq_h, Wq_l, Wtmp32, nullptr, 1024, 1024, 1024, 1024, 1024,
      1024, 0, 0, 0, 0);
  f2h_split<<<1024, 256, 0, stream>>>(Wtmp32, WqrT_h, WqrT_l, 262144);
  gemm_bt<5, 3><<<dim3(8, 8, 1), 256, 0, stream>>>(
      WrT_h, WrT_l, Wk_h, Wk_l, Wtmp32, nullptr, 1024, 1024, 1024, 1024, 1024,
      1024, 0, 0, 0, 0);
  f2h_split<<<1024, 256, 0, stream>>>(Wtmp32, WkrT_h, WkrT_l, 262144);

  // Qhat = cos(query @ Wqr + brq)   [bufC]  (2-pass B: hi then lo)
  gemm_bt<1, 2><<<dim3(8, 128, 1), 256, 0, stream>>>(
      q16, nullptr, WqrT_h, WqrT_l, Qhat, brq, 16384, 1024, 1024, 1024, 1024,
      1024, 0, 0, 0, 0);
  // Khat = cos(value @ Wkr + brk)   [bufA — q16 dead from here]
  gemm_bt<1, 2><<<dim3(8, 128, 1), 256, 0, stream>>>(
      v16, nullptr, WkrT_h, WkrT_l, Khat, brk, 16384, 1024, 1024, 1024, 1024,
      1024, 0, 0, 0, 0);
  // VT[u][s] = (value @ Wv + bv)^T = Wv^T @ value^T  (row bias bv)  [bufD]
  gemm_bt<2, 1><<<dim3(128, 8, 1), 256, 0, stream>>>(
      WvT, nullptr, v16, nullptr, VT, bv, 1024, 16384, 1024, 1024, 1024, 16384,
      0, 0, 0, 0);

  // softmax stats: per-row max m and 1/sum(exp)
  stats_kernel<<<dim3(64, 2, 4), 256, 0, stream>>>(Qhat, Khat, mpart, lpart);
  stats_merge<<<64, 256, 0, stream>>>(mpart, lpart, marr, linv);

  // per batch: probs = exp(Qhat_z @ Khat_z^T - m)  [bufB — v16 dead],
  //            out_z = (probs @ V_z) * (1/l)
  for (int z = 0; z < NB; ++z) {
    gemm_bt<3, 1><<<dim3(32, 32, 1), 256, 0, stream>>>(
        Qhat + (long)z * 4194304, nullptr, Khat + (long)z * 4194304, nullptr,
        probs, marr + z * 4096, 4096, 4096, 1024, 1024, 1024, 4096, 0, 0, 0, 0);
    gemm_bt<4, 1><<<dim3(8, 32, 1), 256, 0, stream>>>(
        probs, nullptr, VT + (long)z * 4096, nullptr, out + (long)z * 4194304,
        linv + z * 4096, 4096, 1024, 4096, 4096, 16384, 1024, 0, 0, 0, 0);
  }
}

// Round 3
// 1318.406 us; speedup vs baseline: 3.0616x; 3.0616x over previous
//
#include <hip/hip_runtime.h>
#include <hip/hip_bf16.h>
#include <hip/hip_fp16.h>
#include <cstdint>

// ---------------------------------------------------------------------------
// LinearAttention (random-feature cos kernel + softmax attention), MI355X.
// out = softmax(cos(q@Wq@Wr + br) @ cos(v@Wk@Wr + br)^T) @ (v@Wv + bv)
// B=4, S=4096, D=U=F=1024.  All heavy math in fp16 MFMA with fp32 accum.
// Workspace plan (aliased, ~168.2 MB total):
//   bufA: q16 -> Khat          bufB: v16 -> probs(1 batch)
//   bufC: Qhat                 bufD: VT
// ---------------------------------------------------------------------------

typedef _Float16 f16;
typedef _Float16 f16x8 __attribute__((ext_vector_type(8)));
typedef _Float16 f16x4 __attribute__((ext_vector_type(4)));
typedef float f32x4 __attribute__((ext_vector_type(4)));

typedef __attribute__((address_space(1))) unsigned int uas1;
typedef __attribute__((address_space(3))) unsigned int uas3;

#define NB 4
#define SEQ 4096
#define DIM 1024

// async 16B/lane global->LDS. LDS dest must be wave-uniform base (+lane*16).
__device__ __forceinline__ void async_copy16(void* lds, const void* g) {
  __builtin_amdgcn_global_load_lds((uas1*)(uintptr_t)g, (uas3*)(uintptr_t)lds,
                                   16, 0, 0);
}

// LDS tile layout: 128 rows x 32 f16 (64B). 16B chunk c of row r holds global
// chunk (c ^ ((r>>1)&3)) — bank-spread swizzle; reads XOR the same way.
__device__ __forceinline__ int swz_src_col(int c) {
  return (c & 3) ^ ((c >> 3) & 3);  // c = linear chunk id (row = c>>2)
}

// ----------------------------- small kernels ------------------------------

__global__ __launch_bounds__(256) void f2h(const float* __restrict__ in,
                                           f16* __restrict__ out, int n4) {
  int i = blockIdx.x * 256 + threadIdx.x;
  if (i < n4) {
    float4 v = ((const float4*)in)[i];
    f16x4 h = {(f16)v.x, (f16)v.y, (f16)v.z, (f16)v.w};
    ((f16x4*)out)[i] = h;
  }
}

__global__ __launch_bounds__(256) void f2h_split(const float* __restrict__ in,
                                                 f16* __restrict__ hi,
                                                 f16* __restrict__ lo, int n4) {
  int i = blockIdx.x * 256 + threadIdx.x;
  if (i < n4) {
    float4 v = ((const float4*)in)[i];
    f16 h0 = (f16)v.x, h1 = (f16)v.y, h2 = (f16)v.z, h3 = (f16)v.w;
    f16x4 hv = {h0, h1, h2, h3};
    f16x4 lv = {(f16)(v.x - (float)h0), (f16)(v.y - (float)h1),
                (f16)(v.z - (float)h2), (f16)(v.w - (float)h3)};
    ((f16x4*)hi)[i] = hv;
    ((f16x4*)lo)[i] = lv;
  }
}

__global__ void tr_h(const f16* __restrict__ in, f16* __restrict__ out, int R,
                     int C) {
  __shared__ f16 tile[32][33];
  int c0 = blockIdx.x * 32, r0 = blockIdx.y * 32;
  tile[threadIdx.y][threadIdx.x] =
      in[(long)(r0 + threadIdx.y) * C + c0 + threadIdx.x];
  __syncthreads();
  out[(long)(c0 + threadIdx.y) * R + r0 + threadIdx.x] =
      tile[threadIdx.x][threadIdx.y];
}

// bias_eff[f] = br[f] + sum_u bvec[u] * Wr[u][f]   (fp32 exact)
__global__ __launch_bounds__(256) void bias_fold(const float* __restrict__ br,
                                                 const float* __restrict__ bvec,
                                                 const float* __restrict__ Wr,
                                                 float* __restrict__ outb) {
  int f = blockIdx.x * 256 + threadIdx.x;
  float s = br[f];
  for (int u = 0; u < DIM; ++u) s = fmaf(bvec[u], Wr[(long)u * DIM + f], s);
  outb[f] = s;
}

__global__ __launch_bounds__(256) void stats_merge(const float* __restrict__ mp,
                                                   const float* __restrict__ lp,
                                                   float* __restrict__ mo,
                                                   float* __restrict__ li) {
  int i = blockIdx.x * 256 + threadIdx.x;  // 0..16383  (z*4096 + q)
  int z = i >> 12, q = i & 4095;
  float m0 = mp[(long)(z * 2 + 0) * SEQ + q], m1 = mp[(long)(z * 2 + 1) * SEQ + q];
  float l0 = lp[(long)(z * 2 + 0) * SEQ + q], l1 = lp[(long)(z * 2 + 1) * SEQ + q];
  float mm = fmaxf(m0, m1);
  float ll = l0 * __expf(m0 - mm) + l1 * __expf(m1 - mm);
  mo[i] = mm;
  li[i] = 1.0f / ll;
}

__global__ void sentinel(float* out) { out[0] = 12345.0f; }

// ------------------------------- main GEMM --------------------------------
// C[M,N] = epilogue( A@B^T [+ A@Bl^T if DB] [+ Al@B^T if DA] )
// B stored row-major [N,K].  128x128 tile, 4 waves, 4x4 16x16x32 frags/wave.
// EPI: 0 f16  | 1 f16 __cosf(v+aux[col]) | 2 f16 v+aux[row]
//      3 f16 exp(v-aux[row]) | 4 f32 v*aux[row] | 5 f32
template <int EPI, bool DA, bool DB>
__global__ __launch_bounds__(256) void gemm_bt(
    const f16* __restrict__ Ah, const f16* __restrict__ Al,
    const f16* __restrict__ Bh, const f16* __restrict__ Bl,
    void* __restrict__ Cv, const float* __restrict__ aux, int M, int N, int K,
    int lda, int ldb, int ldc, long sA, long sB, long sC, int sAux) {
  __shared__ __align__(16) f16 As[128 * 32];
  __shared__ __align__(16) f16 Als[DA ? 128 * 32 : 8];
  __shared__ __align__(16) f16 Bs[128 * 32];
  __shared__ __align__(16) f16 Bls[DB ? 128 * 32 : 8];
  const int z = blockIdx.z;
  const int tn = blockIdx.x, tm = blockIdx.y;
  const int t = threadIdx.x, w = t >> 6, l = t & 63;
  const int l4 = l >> 4, l15 = l & 15;
  const int wm = w & 1, wn = w >> 1;
  const int cswz = l4 ^ ((l15 >> 1) & 3);  // swizzled chunk col for reads
  f32x4 acc[4][4] = {};

  const f16* Az = Ah + (long)z * sA;
  const f16* Bz = Bh + (long)z * sB;

  for (int kk = 0; kk < K; kk += 32) {
    __syncthreads();
#pragma unroll
    for (int j = 0; j < 2; ++j) {
      const int cb = w * 64 + j * 256;  // wave-uniform base chunk
      const int c = cb + l;             // this lane's 16B chunk
      const long ra = (long)(tm * 128 + (c >> 2)) * lda + kk + swz_src_col(c) * 8;
      const long rb = (long)(tn * 128 + (c >> 2)) * ldb + kk + swz_src_col(c) * 8;
      async_copy16(&As[cb * 8], Az + ra);
      if constexpr (DA) async_copy16(&Als[cb * 8], Al + ra);
      async_copy16(&Bs[cb * 8], Bz + rb);
      if constexpr (DB) async_copy16(&Bls[cb * 8], Bl + rb);
    }
    asm volatile("s_waitcnt vmcnt(0)" ::: "memory");
    __syncthreads();
    f16x8 af[4], bf[4];
#pragma unroll
    for (int i = 0; i < 4; ++i) {
      af[i] = *(const f16x8*)&As[(wm * 64 + i * 16 + l15) * 32 + cswz * 8];
      bf[i] = *(const f16x8*)&Bs[(wn * 64 + i * 16 + l15) * 32 + cswz * 8];
    }
#pragma unroll
    for (int i = 0; i < 4; ++i)
#pragma unroll
      for (int jn = 0; jn < 4; ++jn)
        acc[i][jn] = __builtin_amdgcn_mfma_f32_16x16x32_f16(af[i], bf[jn],
                                                            acc[i][jn], 0, 0, 0);
    if constexpr (DB) {
      f16x8 bl[4];
#pragma unroll
      for (int i = 0; i < 4; ++i)
        bl[i] = *(const f16x8*)&Bls[(wn * 64 + i * 16 + l15) * 32 + cswz * 8];
#pragma unroll
      for (int i = 0; i < 4; ++i)
#pragma unroll
        for (int jn = 0; jn < 4; ++jn)
          acc[i][jn] = __builtin_amdgcn_mfma_f32_16x16x32_f16(af[i], bl[jn],
                                                              acc[i][jn], 0, 0, 0);
    }
    if constexpr (DA) {
      f16x8 al[4];
#pragma unroll
      for (int i = 0; i < 4; ++i)
        al[i] = *(const f16x8*)&Als[(wm * 64 + i * 16 + l15) * 32 + cswz * 8];
#pragma unroll
      for (int i = 0; i < 4; ++i)
#pragma unroll
        for (int jn = 0; jn < 4; ++jn)
          acc[i][jn] = __builtin_amdgcn_mfma_f32_16x16x32_f16(al[i], bf[jn],
                                                              acc[i][jn], 0, 0, 0);
    }
  }

  const float* auxp = aux + (long)z * sAux;
#pragma unroll
  for (int i = 0; i < 4; ++i) {
    const int row0 = tm * 128 + wm * 64 + i * 16 + l4 * 4;
#pragma unroll
    for (int jn = 0; jn < 4; ++jn) {
      const int col = tn * 128 + wn * 64 + jn * 16 + l15;
#pragma unroll
      for (int r = 0; r < 4; ++r) {
        const int row = row0 + r;
        float v = acc[i][jn][r];
        if constexpr (EPI == 0) {
          ((f16*)Cv)[(long)z * sC + (long)row * ldc + col] = (f16)v;
        } else if constexpr (EPI == 1) {
          ((f16*)Cv)[(long)z * sC + (long)row * ldc + col] =
              (f16)__cosf(v + auxp[col]);
        } else if constexpr (EPI == 2) {
          ((f16*)Cv)[(long)z * sC + (long)row * ldc + col] =
              (f16)(v + auxp[row]);
        } else if constexpr (EPI == 3) {
          ((f16*)Cv)[(long)z * sC + (long)row * ldc + col] =
              (f16)__expf(v - auxp[row]);
        } else if constexpr (EPI == 4) {
          ((float*)Cv)[(long)z * sC + (long)row * ldc + col] = v * auxp[row];
        } else {
          ((float*)Cv)[(long)z * sC + (long)row * ldc + col] = v;
        }
      }
    }
  }
}

// ------------------------- softmax statistics pass -------------------------
// grid (S/64, 2 key-halves, B); 256 thr. Per WG: 64 q-rows, 2048 keys.
// Online max/sum over k-tiles of 128. Writes partial m,l per (batch,half).
__global__ __launch_bounds__(256) void stats_kernel(const f16* __restrict__ Qh,
                                                    const f16* __restrict__ Kh,
                                                    float* __restrict__ m_part,
                                                    float* __restrict__ l_part) {
  __shared__ __align__(16) f16 Qs[64 * 32];
  __shared__ __align__(16) f16 Ks[128 * 32];
  __shared__ float red[2][64];
  __shared__ float mnew_s[64], mrun[64], lrun[64];
  const int z = blockIdx.z, ky = blockIdx.y, qt = blockIdx.x;
  const f16* Qb = Qh + (long)z * SEQ * DIM + (long)qt * 64 * DIM;
  const f16* Kb = Kh + (long)z * SEQ * DIM + (long)ky * 2048 * DIM;
  const int t = threadIdx.x, w = t >> 6, l = t & 63;
  const int l4 = l >> 4, l15 = l & 15;
  const int wm = w & 1, wn = w >> 1;
  const int cswz = l4 ^ ((l15 >> 1) & 3);
  if (t < 64) {
    mrun[t] = -1e30f;
    lrun[t] = 0.f;
  }
  for (int kt = 0; kt < 16; ++kt) {
    f32x4 acc[2][4] = {};
    for (int f = 0; f < DIM; f += 32) {
      __syncthreads();
      {
        const int cb = w * 64, c = cb + l;  // 256 chunks of Qs
        async_copy16(&Qs[cb * 8],
                     Qb + (long)(c >> 2) * DIM + f + swz_src_col(c) * 8);
      }
#pragma unroll
      for (int j = 0; j < 2; ++j) {  // 512 chunks of Ks
        const int cb = (j * 4 + w) * 64, c = cb + l;
        async_copy16(&Ks[cb * 8], Kb + (long)(kt * 128 + (c >> 2)) * DIM + f +
                                      swz_src_col(c) * 8);
      }
      asm volatile("s_waitcnt vmcnt(0)" ::: "memory");
      __syncthreads();
      f16x8 af[2], bf[4];
#pragma unroll
      for (int i = 0; i < 2; ++i)
        af[i] = *(const f16x8*)&Qs[(wm * 32 + i * 16 + l15) * 32 + cswz * 8];
#pragma unroll
      for (int i = 0; i < 4; ++i)
        bf[i] = *(const f16x8*)&Ks[(wn * 64 + i * 16 + l15) * 32 + cswz * 8];
#pragma unroll
      for (int i = 0; i < 2; ++i)
#pragma unroll
        for (int jn = 0; jn < 4; ++jn)
          acc[i][jn] = __builtin_amdgcn_mfma_f32_16x16x32_f16(af[i], bf[jn],
                                                              acc[i][jn], 0, 0, 0);
    }
    // per-row tile max  (row = wm*32 + i*16 + l4*4 + r, cols across jn & l15)
#pragma unroll
    for (int i = 0; i < 2; ++i)
#pragma unroll
      for (int r = 0; r < 4; ++r) {
        float v = fmaxf(fmaxf(acc[i][0][r], acc[i][1][r]),
                        fmaxf(acc[i][2][r], acc[i][3][r]));
        v = fmaxf(v, __shfl_xor(v, 1));
        v = fmaxf(v, __shfl_xor(v, 2));
        v = fmaxf(v, __shfl_xor(v, 4));
        v = fmaxf(v, __shfl_xor(v, 8));
        if (l15 == 0) red[wn][wm * 32 + i * 16 + l4 * 4 + r] = v;
      }
    __syncthreads();
    if (t < 64) mnew_s[t] = fmaxf(mrun[t], fmaxf(red[0][t], red[1][t]));
    __syncthreads();
#pragma unroll
    for (int i = 0; i < 2; ++i)
#pragma unroll
      for (int r = 0; r < 4; ++r) {
        const float mn = mnew_s[wm * 32 + i * 16 + l4 * 4 + r];
        float s = __expf(acc[i][0][r] - mn) + __expf(acc[i][1][r] - mn) +
                  __expf(acc[i][2][r] - mn) + __expf(acc[i][3][r] - mn);
        s += __shfl_xor(s, 1);
        s += __shfl_xor(s, 2);
        s += __shfl_xor(s, 4);
        s += __shfl_xor(s, 8);
        if (l15 == 0) red[wn][wm * 32 + i * 16 + l4 * 4 + r] = s;
      }
    __syncthreads();
    if (t < 64) {
      lrun[t] = lrun[t] * __expf(mrun[t] - mnew_s[t]) + red[0][t] + red[1][t];
      mrun[t] = mnew_s[t];
    }
    __syncthreads();
  }
  if (t < 64) {
    const long o = (long)(z * 2 + ky) * SEQ + qt * 64 + t;
    m_part[o] = mrun[t];
    l_part[o] = lrun[t];
  }
}

// --------------------------------- driver ----------------------------------

extern "C" void kernel_launch(void* const* d_in, const int* in_sizes, int n_in,
                              void* d_out, int out_size, void* d_ws,
                              size_t ws_size, hipStream_t stream) {
  const float* query = (const float*)d_in[0];
  const float* value = (const float*)d_in[1];
  const float* Wq = (const float*)d_in[2];
  const float* bq = (const float*)d_in[3];
  const float* Wk = (const float*)d_in[4];
  const float* bk = (const float*)d_in[5];
  const float* Wv = (const float*)d_in[6];
  const float* bv = (const float*)d_in[7];
  const float* Wr = (const float*)d_in[8];
  const float* br = (const float*)d_in[9];
  float* out = (float*)d_out;

  // ws budget check: total below is 168,173,568 bytes (+ padding slack).
  if (ws_size < 169000000ull) {
    sentinel<<<1, 1, 0, stream>>>(out);
    return;
  }

  char* p = (char*)d_ws;
  auto alloc = [&](size_t bytes) {
    char* r = p;
    p += (bytes + 255) & ~(size_t)255;
    return r;
  };
  const size_t QV = 16777216ull;  // B*S*D elements
  const size_t WW = 1048576ull;   // 1024*1024 elements
  char* bufA = alloc(QV * 2);  // q16 -> Khat
  char* bufB = alloc(QV * 2);  // v16 -> probs (one batch: 4096*4096*2 = 32MB)
  char* bufC = alloc(QV * 2);  // Qhat
  char* bufD = alloc(QV * 2);  // VT
  f16* q16 = (f16*)bufA;
  f16* Khat = (f16*)bufA;
  f16* v16 = (f16*)bufB;
  f16* probs = (f16*)bufB;
  f16* Qhat = (f16*)bufC;
  f16* VT = (f16*)bufD;
  f16* Wq_h = (f16*)alloc(WW * 2);
  f16* Wq_l = (f16*)alloc(WW * 2);
  f16* Wk_h = (f16*)alloc(WW * 2);
  f16* Wk_l = (f16*)alloc(WW * 2);
  f16* Wr_h = (f16*)alloc(WW * 2);
  f16* Wr_l = (f16*)alloc(WW * 2);
  f16* Wv16 = (f16*)alloc(WW * 2);
  f16* WrT_h = (f16*)alloc(WW * 2);
  f16* WrT_l = (f16*)alloc(WW * 2);
  f16* WvT = (f16*)alloc(WW * 2);
  float* Wtmp32 = (float*)alloc(WW * 4);
  f16* WqrT_h = (f16*)alloc(WW * 2);
  f16* WqrT_l = (f16*)alloc(WW * 2);
  f16* WkrT_h = (f16*)alloc(WW * 2);
  f16* WkrT_l = (f16*)alloc(WW * 2);
  float* brq = (float*)alloc(1024 * 4);
  float* brk = (float*)alloc(1024 * 4);
  float* mpart = (float*)alloc(8 * 4096 * 4);
  float* lpart = (float*)alloc(8 * 4096 * 4);
  float* marr = (float*)alloc(16384 * 4);
  float* linv = (float*)alloc(16384 * 4);

  // fp32 -> fp16 conversions (split for W matrices feeding Wqr/Wkr)
  f2h<<<16384, 256, 0, stream>>>(query, q16, 4194304);
  f2h<<<16384, 256, 0, stream>>>(value, v16, 4194304);
  f2h_split<<<1024, 256, 0, stream>>>(Wq, Wq_h, Wq_l, 262144);
  f2h_split<<<1024, 256, 0, stream>>>(Wk, Wk_h, Wk_l, 262144);
  f2h_split<<<1024, 256, 0, stream>>>(Wr, Wr_h, Wr_l, 262144);
  f2h<<<1024, 256, 0, stream>>>(Wv, Wv16, 262144);
  tr_h<<<dim3(32, 32), dim3(32, 32), 0, stream>>>(Wr_h, WrT_h, 1024, 1024);
  tr_h<<<dim3(32, 32), dim3(32, 32), 0, stream>>>(Wr_l, WrT_l, 1024, 1024);
  tr_h<<<dim3(32, 32), dim3(32, 32), 0, stream>>>(Wv16, WvT, 1024, 1024);
  bias_fold<<<4, 256, 0, stream>>>(br, bq, Wr, brq);
  bias_fold<<<4, 256, 0, stream>>>(br, bk, Wr, brk);

  // WqrT = Wr^T @ Wq^T in ~fp32 (Ah@Bh + Ah@Bl + Al@Bh), split to f16 hi/lo
  gemm_bt<5, true, true><<<dim3(8, 8, 1), 256, 0, stream>>>(
      WrT_h, WrT_l, Wq_h, Wq_l, Wtmp32, nullptr, 1024, 1024, 1024, 1024, 1024,
      1024, 0, 0, 0, 0);
  f2h_split<<<1024, 256, 0, stream>>>(Wtmp32, WqrT_h, WqrT_l, 262144);
  gemm_bt<5, true, true><<<dim3(8, 8, 1), 256, 0, stream>>>(
      WrT_h, WrT_l, Wk_h, Wk_l, Wtmp32, nullptr, 1024, 1024, 1024, 1024, 1024,
      1024, 0, 0, 0, 0);
  f2h_split<<<1024, 256, 0, stream>>>(Wtmp32, WkrT_h, WkrT_l, 262144);

  // Qhat = cos(query @ Wqr + brq)   [bufC]  (B = hi + lo, fused dual-B)
  gemm_bt<1, false, true><<<dim3(8, 128, 1), 256, 0, stream>>>(
      q16, nullptr, WqrT_h, WqrT_l, Qhat, brq, 16384, 1024, 1024, 1024, 1024,
      1024, 0, 0, 0, 0);
  // Khat = cos(value @ Wkr + brk)   [bufA — q16 dead from here]
  gemm_bt<1, false, true><<<dim3(8, 128, 1), 256, 0, stream>>>(
      v16, nullptr, WkrT_h, WkrT_l, Khat, brk, 16384, 1024, 1024, 1024, 1024,
      1024, 0, 0, 0, 0);
  // VT[u][s] = (value @ Wv + bv)^T = Wv^T @ value^T  (row bias bv)  [bufD]
  gemm_bt<2, false, false><<<dim3(128, 8, 1), 256, 0, stream>>>(
      WvT, nullptr, v16, nullptr, VT, bv, 1024, 16384, 1024, 1024, 1024, 16384,
      0, 0, 0, 0);

  // softmax stats: per-row max m and 1/sum(exp)
  stats_kernel<<<dim3(64, 2, 4), 256, 0, stream>>>(Qhat, Khat, mpart, lpart);
  stats_merge<<<64, 256, 0, stream>>>(mpart, lpart, marr, linv);

  // per batch: probs = exp(Qhat_z @ Khat_z^T - m)  [bufB — v16 dead],
  //            out_z = (probs @ V_z) * (1/l)
  for (int z = 0; z < NB; ++z) {
    gemm_bt<3, false, false><<<dim3(32, 32, 1), 256, 0, stream>>>(
        Qhat + (long)z * 4194304, nullptr, Khat + (long)z * 4194304, nullptr,
        probs, marr + z * 4096, 4096, 4096, 1024, 1024, 1024, 4096, 0, 0, 0, 0);
    gemm_bt<4, false, false><<<dim3(8, 32, 1), 256, 0, stream>>>(
        probs, nullptr, VT + (long)z * 4096, nullptr, out + (long)z * 4194304,
        linv + z * 4096, 4096, 1024, 4096, 4096, 16384, 1024, 0, 0, 0, 0);
  }
}

// Round 4
// 968.594 us; speedup vs baseline: 4.1673x; 1.3612x over previous
//
#include <hip/hip_runtime.h>
#include <hip/hip_bf16.h>
#include <hip/hip_fp16.h>
#include <cstdint>

// ---------------------------------------------------------------------------
// LinearAttention (random-feature cos kernel + softmax attention), MI355X.
// out = softmax(cos(q@Wq@Wr + br) @ cos(v@Wk@Wr + br)^T) @ (v@Wv + bv)
// B=4, S=4096, D=U=F=1024.  All heavy math in fp16 MFMA with fp32 accum.
// Softmax via tile-local max in the QK^T GEMM epilogue + global fix-up
// (merge + rescale) — no separate stats pass.
// Workspace (aliased, ~163 MB):
//   bufA: q16 -> Khat     bufB: v16 -> probs(z even)   bufC: Qhat
//   bufD: VT              weights region (32MB) -> probs(z odd)
// ---------------------------------------------------------------------------

typedef _Float16 f16;
typedef _Float16 f16x8 __attribute__((ext_vector_type(8)));
typedef _Float16 f16x4 __attribute__((ext_vector_type(4)));
typedef float f32x4 __attribute__((ext_vector_type(4)));

typedef __attribute__((address_space(1))) unsigned int uas1;
typedef __attribute__((address_space(3))) unsigned int uas3;

#define NB 4
#define SEQ 4096
#define DIM 1024

// async 16B/lane global->LDS. LDS dest must be wave-uniform base (+lane*16).
__device__ __forceinline__ void async_copy16(void* lds, const void* g) {
  __builtin_amdgcn_global_load_lds((uas1*)(uintptr_t)g, (uas3*)(uintptr_t)lds,
                                   16, 0, 0);
}

// LDS tile layout: 128 rows x 32 f16 (64B). 16B chunk c of row r holds global
// chunk (c ^ ((r>>1)&3)) — bank-spread swizzle; reads XOR the same way.
__device__ __forceinline__ int swz_src_col(int c) {
  return (c & 3) ^ ((c >> 3) & 3);  // c = linear chunk id (row = c>>2)
}

// ----------------------------- small kernels ------------------------------

__global__ __launch_bounds__(256) void f2h(const float* __restrict__ in,
                                           f16* __restrict__ out, int n4) {
  int i = blockIdx.x * 256 + threadIdx.x;
  if (i < n4) {
    float4 v = ((const float4*)in)[i];
    f16x4 h = {(f16)v.x, (f16)v.y, (f16)v.z, (f16)v.w};
    ((f16x4*)out)[i] = h;
  }
}

__global__ __launch_bounds__(256) void f2h_split(const float* __restrict__ in,
                                                 f16* __restrict__ hi,
                                                 f16* __restrict__ lo, int n4) {
  int i = blockIdx.x * 256 + threadIdx.x;
  if (i < n4) {
    float4 v = ((const float4*)in)[i];
    f16 h0 = (f16)v.x, h1 = (f16)v.y, h2 = (f16)v.z, h3 = (f16)v.w;
    f16x4 hv = {h0, h1, h2, h3};
    f16x4 lv = {(f16)(v.x - (float)h0), (f16)(v.y - (float)h1),
                (f16)(v.z - (float)h2), (f16)(v.w - (float)h3)};
    ((f16x4*)hi)[i] = hv;
    ((f16x4*)lo)[i] = lv;
  }
}

__global__ void tr_h(const f16* __restrict__ in, f16* __restrict__ out, int R,
                     int C) {
  __shared__ f16 tile[32][33];
  int c0 = blockIdx.x * 32, r0 = blockIdx.y * 32;
  tile[threadIdx.y][threadIdx.x] =
      in[(long)(r0 + threadIdx.y) * C + c0 + threadIdx.x];
  __syncthreads();
  out[(long)(c0 + threadIdx.y) * R + r0 + threadIdx.x] =
      tile[threadIdx.x][threadIdx.y];
}

// bias_eff[f] = br[f] + sum_u bvec[u] * Wr[u][f]   (fp32 exact)
__global__ __launch_bounds__(256) void bias_fold(const float* __restrict__ br,
                                                 const float* __restrict__ bvec,
                                                 const float* __restrict__ Wr,
                                                 float* __restrict__ outb) {
  int f = blockIdx.x * 256 + threadIdx.x;
  float s = br[f];
  for (int u = 0; u < DIM; ++u) s = fmaf(bvec[u], Wr[(long)u * DIM + f], s);
  outb[f] = s;
}

// per (z2,row): global max over 32 tile-maxes, scale_t=exp(m_t-m), linv=1/sum
__global__ __launch_bounds__(256) void merge_pair(const float* __restrict__ ml,
                                                  const float* __restrict__ ll,
                                                  f16* __restrict__ scale,
                                                  float* __restrict__ linv) {
  int i = blockIdx.x * 256 + threadIdx.x;  // 0..8191 = z2*4096 + row
  int z2 = i >> 12, row = i & 4095;
  const float* m = ml + z2 * 131072 + row;
  const float* lp = ll + z2 * 131072 + row;
  float mg = -1e30f;
  for (int t = 0; t < 32; ++t) mg = fmaxf(mg, m[t * 4096]);
  float l = 0.f;
  for (int t = 0; t < 32; ++t) {
    float a = __expf(m[t * 4096] - mg);
    scale[z2 * 131072 + t * 4096 + row] = (f16)a;
    l += lp[t * 4096] * a;
  }
  linv[i] = 1.0f / l;
}

// probs[z2,row,col] *= scale[z2, col>>7, row]   (8 f16 per thread)
__global__ __launch_bounds__(256) void rescale(f16* __restrict__ probs0,
                                               const f16* __restrict__ scale,
                                               long strideZ) {
  long idx8 = (long)blockIdx.x * 256 + threadIdx.x;  // 4,194,304 threads
  long base = idx8 * 8;
  int z2 = (int)(base >> 24);
  int within = (int)(base & 16777215);
  int row = within >> 12, col = within & 4095;
  f16 s = scale[z2 * 131072 + (col >> 7) * 4096 + row];
  f16x8* p = (f16x8*)(probs0 + (long)z2 * strideZ + within);
  f16x8 v = *p;
#pragma unroll
  for (int k = 0; k < 8; ++k) v[k] = v[k] * s;
  *p = v;
}

__global__ void sentinel(float* out) { out[0] = 12345.0f; }

// ------------------------------- main GEMM --------------------------------
// C[M,N] = epilogue( A@B^T [+ A@Bl^T if DB] [+ Al@B^T if DA] )
// B stored row-major [N,K].  128x128 tile, 4 waves, 4x4 16x16x32 frags/wave.
// EPI: 0 f16  | 1 f16 __cosf(v+aux[col]) | 2 f16 v+aux[row]
//      4 f32 v*aux[row] | 5 f32
//      6 f16 exp(v - rowmax_tile) + write mout/lout per (z,tn,row)
template <int EPI, bool DA, bool DB>
__global__ __launch_bounds__(256) void gemm_bt(
    const f16* __restrict__ Ah, const f16* __restrict__ Al,
    const f16* __restrict__ Bh, const f16* __restrict__ Bl,
    void* __restrict__ Cv, const float* __restrict__ aux,
    float* __restrict__ mout, float* __restrict__ lout, int M, int N, int K,
    int lda, int ldb, int ldc, long sA, long sB, long sC, int sAux) {
  __shared__ __align__(16) f16 As[128 * 32];
  __shared__ __align__(16) f16 Als[DA ? 128 * 32 : 8];
  __shared__ __align__(16) f16 Bs[128 * 32];
  __shared__ __align__(16) f16 Bls[DB ? 128 * 32 : 8];
  __shared__ float red6[2][128];
  const int z = blockIdx.z;
  const int tn = blockIdx.x, tm = blockIdx.y;
  const int t = threadIdx.x, w = t >> 6, l = t & 63;
  const int l4 = l >> 4, l15 = l & 15;
  const int wm = w & 1, wn = w >> 1;
  const int cswz = l4 ^ ((l15 >> 1) & 3);  // swizzled chunk col for reads
  f32x4 acc[4][4] = {};

  const f16* Az = Ah + (long)z * sA;
  const f16* Bz = Bh + (long)z * sB;
  const f16* Alz = nullptr;
  const f16* Blz = nullptr;
  if constexpr (DA) Alz = Al + (long)z * sA;
  if constexpr (DB) Blz = Bl + (long)z * sB;

  for (int kk = 0; kk < K; kk += 32) {
    __syncthreads();
#pragma unroll
    for (int j = 0; j < 2; ++j) {
      const int cb = w * 64 + j * 256;  // wave-uniform base chunk
      const int c = cb + l;             // this lane's 16B chunk
      const long ra = (long)(tm * 128 + (c >> 2)) * lda + kk + swz_src_col(c) * 8;
      const long rb = (long)(tn * 128 + (c >> 2)) * ldb + kk + swz_src_col(c) * 8;
      async_copy16(&As[cb * 8], Az + ra);
      if constexpr (DA) async_copy16(&Als[cb * 8], Alz + ra);
      async_copy16(&Bs[cb * 8], Bz + rb);
      if constexpr (DB) async_copy16(&Bls[cb * 8], Blz + rb);
    }
    asm volatile("s_waitcnt vmcnt(0)" ::: "memory");
    __syncthreads();
    f16x8 af[4], bf[4];
#pragma unroll
    for (int i = 0; i < 4; ++i) {
      af[i] = *(const f16x8*)&As[(wm * 64 + i * 16 + l15) * 32 + cswz * 8];
      bf[i] = *(const f16x8*)&Bs[(wn * 64 + i * 16 + l15) * 32 + cswz * 8];
    }
#pragma unroll
    for (int i = 0; i < 4; ++i)
#pragma unroll
      for (int jn = 0; jn < 4; ++jn)
        acc[i][jn] = __builtin_amdgcn_mfma_f32_16x16x32_f16(af[i], bf[jn],
                                                            acc[i][jn], 0, 0, 0);
    if constexpr (DB) {
      f16x8 bl[4];
#pragma unroll
      for (int i = 0; i < 4; ++i)
        bl[i] = *(const f16x8*)&Bls[(wn * 64 + i * 16 + l15) * 32 + cswz * 8];
#pragma unroll
      for (int i = 0; i < 4; ++i)
#pragma unroll
        for (int jn = 0; jn < 4; ++jn)
          acc[i][jn] = __builtin_amdgcn_mfma_f32_16x16x32_f16(af[i], bl[jn],
                                                              acc[i][jn], 0, 0, 0);
    }
    if constexpr (DA) {
      f16x8 al[4];
#pragma unroll
      for (int i = 0; i < 4; ++i)
        al[i] = *(const f16x8*)&Als[(wm * 64 + i * 16 + l15) * 32 + cswz * 8];
#pragma unroll
      for (int i = 0; i < 4; ++i)
#pragma unroll
        for (int jn = 0; jn < 4; ++jn)
          acc[i][jn] = __builtin_amdgcn_mfma_f32_16x16x32_f16(al[i], bf[jn],
                                                              acc[i][jn], 0, 0, 0);
    }
  }

  if constexpr (EPI == 6) {
    // ---- tile-local softmax: per-row max over this 128-col tile ----
    float mrow[16];
#pragma unroll
    for (int i = 0; i < 4; ++i)
#pragma unroll
      for (int r = 0; r < 4; ++r) {
        float v = fmaxf(fmaxf(acc[i][0][r], acc[i][1][r]),
                        fmaxf(acc[i][2][r], acc[i][3][r]));
        v = fmaxf(v, __shfl_xor(v, 1));
        v = fmaxf(v, __shfl_xor(v, 2));
        v = fmaxf(v, __shfl_xor(v, 4));
        v = fmaxf(v, __shfl_xor(v, 8));
        if (l15 == 0) red6[wn][wm * 64 + i * 16 + l4 * 4 + r] = v;
      }
    __syncthreads();
#pragma unroll
    for (int i = 0; i < 4; ++i)
#pragma unroll
      for (int r = 0; r < 4; ++r) {
        const int rin = wm * 64 + i * 16 + l4 * 4 + r;
        mrow[i * 4 + r] = fmaxf(red6[0][rin], red6[1][rin]);
      }
    __syncthreads();
    // exp in place + per-row tile sum
#pragma unroll
    for (int i = 0; i < 4; ++i)
#pragma unroll
      for (int r = 0; r < 4; ++r) {
        const float mn = mrow[i * 4 + r];
        float s = 0.f;
#pragma unroll
        for (int jn = 0; jn < 4; ++jn) {
          float e = __expf(acc[i][jn][r] - mn);
          acc[i][jn][r] = e;
          s += e;
        }
        s += __shfl_xor(s, 1);
        s += __shfl_xor(s, 2);
        s += __shfl_xor(s, 4);
        s += __shfl_xor(s, 8);
        if (l15 == 0) red6[wn][wm * 64 + i * 16 + l4 * 4 + r] = s;
      }
    __syncthreads();
    // write unnormalized probs
#pragma unroll
    for (int i = 0; i < 4; ++i) {
      const int row0 = tm * 128 + wm * 64 + i * 16 + l4 * 4;
#pragma unroll
      for (int jn = 0; jn < 4; ++jn) {
        const int col = tn * 128 + wn * 64 + jn * 16 + l15;
#pragma unroll
        for (int r = 0; r < 4; ++r)
          ((f16*)Cv)[(long)z * sC + (long)(row0 + r) * ldc + col] =
              (f16)acc[i][jn][r];
      }
    }
    // write per-(row,tile) stats
    if (wn == 0 && l15 == 0) {
#pragma unroll
      for (int i = 0; i < 4; ++i)
#pragma unroll
        for (int r = 0; r < 4; ++r) {
          const int rin = wm * 64 + i * 16 + l4 * 4 + r;
          const int gidx = z * 131072 + tn * 4096 + tm * 128 + rin;
          mout[gidx] = mrow[i * 4 + r];
          lout[gidx] = red6[0][rin] + red6[1][rin];
        }
    }
    return;
  }

  const float* auxp = aux + (long)z * sAux;
#pragma unroll
  for (int i = 0; i < 4; ++i) {
    const int row0 = tm * 128 + wm * 64 + i * 16 + l4 * 4;
#pragma unroll
    for (int jn = 0; jn < 4; ++jn) {
      const int col = tn * 128 + wn * 64 + jn * 16 + l15;
#pragma unroll
      for (int r = 0; r < 4; ++r) {
        const int row = row0 + r;
        float v = acc[i][jn][r];
        if constexpr (EPI == 0) {
          ((f16*)Cv)[(long)z * sC + (long)row * ldc + col] = (f16)v;
        } else if constexpr (EPI == 1) {
          ((f16*)Cv)[(long)z * sC + (long)row * ldc + col] =
              (f16)__cosf(v + auxp[col]);
        } else if constexpr (EPI == 2) {
          ((f16*)Cv)[(long)z * sC + (long)row * ldc + col] =
              (f16)(v + auxp[row]);
        } else if constexpr (EPI == 4) {
          ((float*)Cv)[(long)z * sC + (long)row * ldc + col] = v * auxp[row];
        } else {
          ((float*)Cv)[(long)z * sC + (long)row * ldc + col] = v;
        }
      }
    }
  }
}

// --------------------------------- driver ----------------------------------

extern "C" void kernel_launch(void* const* d_in, const int* in_sizes, int n_in,
                              void* d_out, int out_size, void* d_ws,
                              size_t ws_size, hipStream_t stream) {
  const float* query = (const float*)d_in[0];
  const float* value = (const float*)d_in[1];
  const float* Wq = (const float*)d_in[2];
  const float* bq = (const float*)d_in[3];
  const float* Wk = (const float*)d_in[4];
  const float* bk = (const float*)d_in[5];
  const float* Wv = (const float*)d_in[6];
  const float* bv = (const float*)d_in[7];
  const float* Wr = (const float*)d_in[8];
  const float* br = (const float*)d_in[9];
  float* out = (float*)d_out;

  if (ws_size < 169000000ull) {
    sentinel<<<1, 1, 0, stream>>>(out);
    return;
  }

  char* p = (char*)d_ws;
  auto alloc = [&](size_t bytes) {
    char* r = p;
    p += (bytes + 255) & ~(size_t)255;
    return r;
  };
  const size_t QV = 16777216ull;  // B*S*D elements
  const size_t WW = 1048576ull;   // 1024*1024 elements
  char* bufA = alloc(QV * 2);  // q16 -> Khat
  char* bufB = alloc(QV * 2);  // v16 -> probs z-even (32MB)
  char* bufC = alloc(QV * 2);  // Qhat
  char* bufD = alloc(QV * 2);  // VT
  f16* q16 = (f16*)bufA;
  f16* Khat = (f16*)bufA;
  f16* v16 = (f16*)bufB;
  f16* probs0 = (f16*)bufB;  // pair slot 0; slot 1 = weights region (+96MB)
  f16* Qhat = (f16*)bufC;
  f16* VT = (f16*)bufD;
  // weights region: exactly 32 MB from Wq_h to end of WkrT_l -> probs slot 1
  f16* Wq_h = (f16*)alloc(WW * 2);
  f16* Wq_l = (f16*)alloc(WW * 2);
  f16* Wk_h = (f16*)alloc(WW * 2);
  f16* Wk_l = (f16*)alloc(WW * 2);
  f16* Wr_h = (f16*)alloc(WW * 2);
  f16* Wr_l = (f16*)alloc(WW * 2);
  f16* Wv16 = (f16*)alloc(WW * 2);
  f16* WrT_h = (f16*)alloc(WW * 2);
  f16* WrT_l = (f16*)alloc(WW * 2);
  f16* WvT = (f16*)alloc(WW * 2);
  float* Wtmp32 = (float*)alloc(WW * 4);
  f16* WqrT_h = (f16*)alloc(WW * 2);
  f16* WqrT_l = (f16*)alloc(WW * 2);
  f16* WkrT_h = (f16*)alloc(WW * 2);
  f16* WkrT_l = (f16*)alloc(WW * 2);
  float* brq = (float*)alloc(1024 * 4);
  float* brk = (float*)alloc(1024 * 4);
  float* m_loc = (float*)alloc(2 * 32 * 4096 * 4);  // [z2][tn][row]
  float* l_loc = (float*)alloc(2 * 32 * 4096 * 4);
  f16* scl = (f16*)alloc(2 * 32 * 4096 * 2);
  float* linv = (float*)alloc(2 * 4096 * 4);
  const long PSTRIDE = 50331648;  // f16 elems between probs slot 0 and slot 1

  // fp32 -> fp16 conversions (split for W matrices feeding Wqr/Wkr)
  f2h<<<16384, 256, 0, stream>>>(query, q16, 4194304);
  f2h<<<16384, 256, 0, stream>>>(value, v16, 4194304);
  f2h_split<<<1024, 256, 0, stream>>>(Wq, Wq_h, Wq_l, 262144);
  f2h_split<<<1024, 256, 0, stream>>>(Wk, Wk_h, Wk_l, 262144);
  f2h_split<<<1024, 256, 0, stream>>>(Wr, Wr_h, Wr_l, 262144);
  f2h<<<1024, 256, 0, stream>>>(Wv, Wv16, 262144);
  tr_h<<<dim3(32, 32), dim3(32, 32), 0, stream>>>(Wr_h, WrT_h, 1024, 1024);
  tr_h<<<dim3(32, 32), dim3(32, 32), 0, stream>>>(Wr_l, WrT_l, 1024, 1024);
  tr_h<<<dim3(32, 32), dim3(32, 32), 0, stream>>>(Wv16, WvT, 1024, 1024);
  bias_fold<<<4, 256, 0, stream>>>(br, bq, Wr, brq);
  bias_fold<<<4, 256, 0, stream>>>(br, bk, Wr, brk);

  // WqrT = Wr^T @ Wq^T in ~fp32 (Ah@Bh + Ah@Bl + Al@Bh), split to f16 hi/lo
  gemm_bt<5, true, true><<<dim3(8, 8, 1), 256, 0, stream>>>(
      WrT_h, WrT_l, Wq_h, Wq_l, Wtmp32, nullptr, nullptr, nullptr, 1024, 1024,
      1024, 1024, 1024, 1024, 0, 0, 0, 0);
  f2h_split<<<1024, 256, 0, stream>>>(Wtmp32, WqrT_h, WqrT_l, 262144);
  gemm_bt<5, true, true><<<dim3(8, 8, 1), 256, 0, stream>>>(
      WrT_h, WrT_l, Wk_h, Wk_l, Wtmp32, nullptr, nullptr, nullptr, 1024, 1024,
      1024, 1024, 1024, 1024, 0, 0, 0, 0);
  f2h_split<<<1024, 256, 0, stream>>>(Wtmp32, WkrT_h, WkrT_l, 262144);

  // Qhat = cos(query @ Wqr + brq)   [bufC]  (B = hi + lo, fused dual-B)
  gemm_bt<1, false, true><<<dim3(8, 128, 1), 256, 0, stream>>>(
      q16, nullptr, WqrT_h, WqrT_l, Qhat, brq, nullptr, nullptr, 16384, 1024,
      1024, 1024, 1024, 1024, 0, 0, 0, 0);
  // Khat = cos(value @ Wkr + brk)   [bufA — q16 dead from here]
  gemm_bt<1, false, true><<<dim3(8, 128, 1), 256, 0, stream>>>(
      v16, nullptr, WkrT_h, WkrT_l, Khat, brk, nullptr, nullptr, 16384, 1024,
      1024, 1024, 1024, 1024, 0, 0, 0, 0);
  // VT[u][s] = (value @ Wv + bv)^T = Wv^T @ value^T  (row bias bv)  [bufD]
  gemm_bt<2, false, false><<<dim3(128, 8, 1), 256, 0, stream>>>(
      WvT, nullptr, v16, nullptr, VT, bv, nullptr, nullptr, 1024, 16384, 1024,
      1024, 1024, 16384, 0, 0, 0, 0);

  // per batch-pair: probs = exp(S - m_tile) + stats; merge; rescale; PV
  for (int zb = 0; zb < NB; zb += 2) {
    gemm_bt<6, false, false><<<dim3(32, 32, 2), 256, 0, stream>>>(
        Qhat + (long)zb * 4194304, nullptr, Khat + (long)zb * 4194304, nullptr,
        probs0, nullptr, m_loc, l_loc, 4096, 4096, 1024, 1024, 1024, 4096,
        4194304, 4194304, PSTRIDE, 0);
    merge_pair<<<32, 256, 0, stream>>>(m_loc, l_loc, scl, linv);
    rescale<<<16384, 256, 0, stream>>>(probs0, scl, PSTRIDE);
    gemm_bt<4, false, false><<<dim3(8, 32, 2), 256, 0, stream>>>(
        probs0, nullptr, VT + (long)zb * 4096, nullptr, out + (long)zb * 4194304,
        linv, nullptr, nullptr, 4096, 1024, 4096, 4096, 16384, 1024, PSTRIDE,
        4096, 4194304, 4096);
  }
}

// Round 5
// 899.468 us; speedup vs baseline: 4.4876x; 1.0769x over previous
//
#include <hip/hip_runtime.h>
#include <hip/hip_bf16.h>
#include <hip/hip_fp16.h>
#include <cstdint>

// ---------------------------------------------------------------------------
// LinearAttention (random-feature cos kernel + softmax attention), MI355X.
// out = softmax(cos(q@Wq@Wr + br) @ cos(v@Wk@Wr + br)^T) @ (v@Wv + bv)
// B=4, S=4096, D=U=F=1024.  All heavy math in fp16 MFMA with fp32 accum.
// Softmax: tile-local max in QK^T epilogue (EPI=6) + fold-in of
// alpha_t/l into PV's A-fragments per k-tile (EPI=7). No rescale pass.
// Workspace (aliased, ~166 MB):
//   bufA: q16 -> Khat     bufB: v16 -> probs(z even)   bufC: Qhat
//   bufD: VT              weights region (32MB) -> probs(z odd)
// ---------------------------------------------------------------------------

typedef _Float16 f16;
typedef _Float16 f16x8 __attribute__((ext_vector_type(8)));
typedef _Float16 f16x4 __attribute__((ext_vector_type(4)));
typedef float f32x4 __attribute__((ext_vector_type(4)));

typedef __attribute__((address_space(1))) unsigned int uas1;
typedef __attribute__((address_space(3))) unsigned int uas3;

#define NB 4
#define SEQ 4096
#define DIM 1024

// async 16B/lane global->LDS. LDS dest must be wave-uniform base (+lane*16).
__device__ __forceinline__ void async_copy16(void* lds, const void* g) {
  __builtin_amdgcn_global_load_lds((uas1*)(uintptr_t)g, (uas3*)(uintptr_t)lds,
                                   16, 0, 0);
}

// LDS tile layout: 128 rows x 32 f16 (64B). 16B chunk c of row r holds global
// chunk (c ^ ((r>>1)&3)) — bank-spread swizzle; reads XOR the same way.
__device__ __forceinline__ int swz_src_col(int c) {
  return (c & 3) ^ ((c >> 3) & 3);  // c = linear chunk id (row = c>>2)
}

// ----------------------------- small kernels ------------------------------

__global__ __launch_bounds__(256) void f2h(const float* __restrict__ in,
                                           f16* __restrict__ out, int n4) {
  int i = blockIdx.x * 256 + threadIdx.x;
  if (i < n4) {
    float4 v = ((const float4*)in)[i];
    f16x4 h = {(f16)v.x, (f16)v.y, (f16)v.z, (f16)v.w};
    ((f16x4*)out)[i] = h;
  }
}

__global__ __launch_bounds__(256) void f2h_split(const float* __restrict__ in,
                                                 f16* __restrict__ hi,
                                                 f16* __restrict__ lo, int n4) {
  int i = blockIdx.x * 256 + threadIdx.x;
  if (i < n4) {
    float4 v = ((const float4*)in)[i];
    f16 h0 = (f16)v.x, h1 = (f16)v.y, h2 = (f16)v.z, h3 = (f16)v.w;
    f16x4 hv = {h0, h1, h2, h3};
    f16x4 lv = {(f16)(v.x - (float)h0), (f16)(v.y - (float)h1),
                (f16)(v.z - (float)h2), (f16)(v.w - (float)h3)};
    ((f16x4*)hi)[i] = hv;
    ((f16x4*)lo)[i] = lv;
  }
}

__global__ void tr_h(const f16* __restrict__ in, f16* __restrict__ out, int R,
                     int C) {
  __shared__ f16 tile[32][33];
  int c0 = blockIdx.x * 32, r0 = blockIdx.y * 32;
  tile[threadIdx.y][threadIdx.x] =
      in[(long)(r0 + threadIdx.y) * C + c0 + threadIdx.x];
  __syncthreads();
  out[(long)(c0 + threadIdx.y) * R + r0 + threadIdx.x] =
      tile[threadIdx.x][threadIdx.y];
}

// bias_eff[f] = br[f] + sum_u bvec[u] * Wr[u][f]   (fp32 exact)
__global__ __launch_bounds__(256) void bias_fold(const float* __restrict__ br,
                                                 const float* __restrict__ bvec,
                                                 const float* __restrict__ Wr,
                                                 float* __restrict__ outb) {
  int f = blockIdx.x * 256 + threadIdx.x;
  float s = br[f];
  for (int u = 0; u < DIM; ++u) s = fmaf(bvec[u], Wr[(long)u * DIM + f], s);
  outb[f] = s;
}

// per (z2,row): m = max_t m_t; l = sum_t l_t exp(m_t-m);
// scl[t][row] = exp(m_t-m)/l  (f16)
__global__ __launch_bounds__(256) void merge_pair(const float* __restrict__ ml,
                                                  const float* __restrict__ ll,
                                                  f16* __restrict__ scl) {
  int i = blockIdx.x * 256 + threadIdx.x;  // 0..8191 = z2*4096 + row
  int z2 = i >> 12, row = i & 4095;
  const float* m = ml + z2 * 131072 + row;
  const float* lp = ll + z2 * 131072 + row;
  float a[32];
  float mg = -1e30f;
#pragma unroll 32
  for (int t = 0; t < 32; ++t) mg = fmaxf(mg, m[t * 4096]);
  float l = 0.f;
#pragma unroll 32
  for (int t = 0; t < 32; ++t) {
    a[t] = __expf(m[t * 4096] - mg);
    l += lp[t * 4096] * a[t];
  }
  float li = 1.0f / l;
#pragma unroll 32
  for (int t = 0; t < 32; ++t)
    scl[z2 * 131072 + t * 4096 + row] = (f16)(a[t] * li);
}

__global__ void sentinel(float* out) { out[0] = 12345.0f; }

// ------------------------------- main GEMM --------------------------------
// C[M,N] = epilogue( A@B^T [+ A@Bl^T if DB] [+ Al@B^T if DA] )
// B stored row-major [N,K].  128x128 tile, 4 waves, 4x4 16x16x32 frags/wave.
// EPI: 1 f16 __cosf(v+aux[col]) | 2 f16 v+aux[row] | 5 f32 plain
//      6 f16 exp(v - rowmax_tile) + write mout/lout per (z,tn,row)
//      7 f32 plain, A-fragments scaled by ascl[ktile][arow] per k-tile
// All epilogues write through an LDS repack for vectorized stores.
template <int EPI, bool DA, bool DB>
__global__ __launch_bounds__(256) void gemm_bt(
    const f16* __restrict__ Ah, const f16* __restrict__ Al,
    const f16* __restrict__ Bh, const f16* __restrict__ Bl,
    void* __restrict__ Cv, const float* __restrict__ aux,
    float* __restrict__ mout, float* __restrict__ lout,
    const f16* __restrict__ ascl, long sAscl, int M, int N, int K, int lda,
    int ldb, int ldc, long sA, long sB, long sC, int sAux) {
  constexpr int NSTAGE = 2 + (DA ? 1 : 0) + (DB ? 1 : 0);
  constexpr int STAGE_BYTES = NSTAGE * 8192;
  constexpr int SMEM_BYTES = STAGE_BYTES > 17408 ? STAGE_BYTES : 17408;
  __shared__ __align__(16) char smem[SMEM_BYTES];
  __shared__ float red6[EPI == 6 ? 2 : 1][EPI == 6 ? 128 : 1];
  f16* As = (f16*)smem;
  f16* Bs = (f16*)(smem + 8192);
  f16* Als = (f16*)(smem + 16384);
  f16* Bls = (f16*)(smem + 16384 + (DA ? 8192 : 0));

  const int z = blockIdx.z;
  const int tn = blockIdx.x, tm = blockIdx.y;
  const int t = threadIdx.x, w = t >> 6, l = t & 63;
  const int l4 = l >> 4, l15 = l & 15;
  const int wm = w & 1, wn = w >> 1;
  const int cswz = l4 ^ ((l15 >> 1) & 3);  // swizzled chunk col for reads
  f32x4 acc[4][4] = {};

  const f16* Az = Ah + (long)z * sA;
  const f16* Bz = Bh + (long)z * sB;
  const f16* Alz = nullptr;
  const f16* Blz = nullptr;
  if constexpr (DA) Alz = Al + (long)z * sA;
  if constexpr (DB) Blz = Bl + (long)z * sB;
  const f16* asclz = nullptr;
  if constexpr (EPI == 7) asclz = ascl + (long)z * sAscl;

  f16 sA4[4] = {};

  for (int kk = 0; kk < K; kk += 32) {
    if constexpr (EPI == 7) {
      if ((kk & 127) == 0) {
        const int tile = kk >> 7;
#pragma unroll
        for (int i = 0; i < 4; ++i)
          sA4[i] = asclz[tile * M + tm * 128 + wm * 64 + i * 16 + l15];
      }
    }
    __syncthreads();
#pragma unroll
    for (int j = 0; j < 2; ++j) {
      const int cb = w * 64 + j * 256;  // wave-uniform base chunk
      const int c = cb + l;             // this lane's 16B chunk
      const long ra = (long)(tm * 128 + (c >> 2)) * lda + kk + swz_src_col(c) * 8;
      const long rb = (long)(tn * 128 + (c >> 2)) * ldb + kk + swz_src_col(c) * 8;
      async_copy16(&As[cb * 8], Az + ra);
      if constexpr (DA) async_copy16(&Als[cb * 8], Alz + ra);
      async_copy16(&Bs[cb * 8], Bz + rb);
      if constexpr (DB) async_copy16(&Bls[cb * 8], Blz + rb);
    }
    asm volatile("s_waitcnt vmcnt(0)" ::: "memory");
    __syncthreads();
    f16x8 af[4], bf[4];
#pragma unroll
    for (int i = 0; i < 4; ++i) {
      af[i] = *(const f16x8*)&As[(wm * 64 + i * 16 + l15) * 32 + cswz * 8];
      bf[i] = *(const f16x8*)&Bs[(wn * 64 + i * 16 + l15) * 32 + cswz * 8];
    }
    if constexpr (EPI == 7) {
#pragma unroll
      for (int i = 0; i < 4; ++i) af[i] = af[i] * sA4[i];
    }
#pragma unroll
    for (int i = 0; i < 4; ++i)
#pragma unroll
      for (int jn = 0; jn < 4; ++jn)
        acc[i][jn] = __builtin_amdgcn_mfma_f32_16x16x32_f16(af[i], bf[jn],
                                                            acc[i][jn], 0, 0, 0);
    if constexpr (DB) {
      f16x8 bl[4];
#pragma unroll
      for (int i = 0; i < 4; ++i)
        bl[i] = *(const f16x8*)&Bls[(wn * 64 + i * 16 + l15) * 32 + cswz * 8];
#pragma unroll
      for (int i = 0; i < 4; ++i)
#pragma unroll
        for (int jn = 0; jn < 4; ++jn)
          acc[i][jn] = __builtin_amdgcn_mfma_f32_16x16x32_f16(af[i], bl[jn],
                                                              acc[i][jn], 0, 0, 0);
    }
    if constexpr (DA) {
      f16x8 al[4];
#pragma unroll
      for (int i = 0; i < 4; ++i)
        al[i] = *(const f16x8*)&Als[(wm * 64 + i * 16 + l15) * 32 + cswz * 8];
#pragma unroll
      for (int i = 0; i < 4; ++i)
#pragma unroll
        for (int jn = 0; jn < 4; ++jn)
          acc[i][jn] = __builtin_amdgcn_mfma_f32_16x16x32_f16(al[i], bf[jn],
                                                              acc[i][jn], 0, 0, 0);
    }
  }

  if constexpr (EPI == 6) {
    // ---- tile-local softmax: per-row max over this 128-col tile ----
    float mrow[16];
#pragma unroll
    for (int i = 0; i < 4; ++i)
#pragma unroll
      for (int r = 0; r < 4; ++r) {
        float v = fmaxf(fmaxf(acc[i][0][r], acc[i][1][r]),
                        fmaxf(acc[i][2][r], acc[i][3][r]));
        v = fmaxf(v, __shfl_xor(v, 1));
        v = fmaxf(v, __shfl_xor(v, 2));
        v = fmaxf(v, __shfl_xor(v, 4));
        v = fmaxf(v, __shfl_xor(v, 8));
        if (l15 == 0) red6[wn][wm * 64 + i * 16 + l4 * 4 + r] = v;
      }
    __syncthreads();
#pragma unroll
    for (int i = 0; i < 4; ++i)
#pragma unroll
      for (int r = 0; r < 4; ++r) {
        const int rin = wm * 64 + i * 16 + l4 * 4 + r;
        mrow[i * 4 + r] = fmaxf(red6[0][rin], red6[1][rin]);
      }
    __syncthreads();
    // exp in place + per-row tile sum
#pragma unroll
    for (int i = 0; i < 4; ++i)
#pragma unroll
      for (int r = 0; r < 4; ++r) {
        const float mn = mrow[i * 4 + r];
        float s = 0.f;
#pragma unroll
        for (int jn = 0; jn < 4; ++jn) {
          float e = __expf(acc[i][jn][r] - mn);
          acc[i][jn][r] = e;
          s += e;
        }
        s += __shfl_xor(s, 1);
        s += __shfl_xor(s, 2);
        s += __shfl_xor(s, 4);
        s += __shfl_xor(s, 8);
        if (l15 == 0) red6[wn][wm * 64 + i * 16 + l4 * 4 + r] = s;
      }
    __syncthreads();
    if (wn == 0 && l15 == 0) {
#pragma unroll
      for (int i = 0; i < 4; ++i)
#pragma unroll
        for (int r = 0; r < 4; ++r) {
          const int rin = wm * 64 + i * 16 + l4 * 4 + r;
          const int gidx = z * 131072 + tn * 4096 + tm * 128 + rin;
          mout[gidx] = mrow[i * 4 + r];
          lout[gidx] = red6[0][rin] + red6[1][rin];
        }
    }
  }

  const float* auxp = aux + (long)z * sAux;

  if constexpr (EPI == 1 || EPI == 2 || EPI == 6) {
    // ---- f16 output via LDS repack: [64][136] per half ----
    f16* rep = (f16*)smem;
#pragma unroll
    for (int hh = 0; hh < 2; ++hh) {
      __syncthreads();
#pragma unroll
      for (int ii = 0; ii < 2; ++ii) {
        const int i = hh * 2 + ii;
        const int lrow0 = wm * 32 + ii * 16 + l4 * 4;
#pragma unroll
        for (int jn = 0; jn < 4; ++jn) {
          const int col = wn * 64 + jn * 16 + l15;
#pragma unroll
          for (int r = 0; r < 4; ++r) {
            float v = acc[i][jn][r];
            f16 hv;
            if constexpr (EPI == 1)
              hv = (f16)__cosf(v + auxp[tn * 128 + col]);
            else if constexpr (EPI == 2)
              hv = (f16)(v + auxp[tm * 128 + wm * 64 + i * 16 + l4 * 4 + r]);
            else
              hv = (f16)v;
            rep[(lrow0 + r) * 136 + col] = hv;
          }
        }
      }
      __syncthreads();
#pragma unroll
      for (int pp = 0; pp < 4; ++pp) {
        const int lrow = pp * 16 + (t >> 4);
        const int grow = tm * 128 + (lrow >> 5) * 64 + hh * 32 + (lrow & 31);
        const int gcol = tn * 128 + (t & 15) * 8;
        *(f16x8*)&((f16*)Cv)[(long)z * sC + (long)grow * ldc + gcol] =
            *(const f16x8*)&rep[lrow * 136 + (t & 15) * 8];
      }
    }
  } else {
    // ---- f32 output via LDS repack: [32][132] per i-group ----
    float* rep = (float*)smem;
#pragma unroll
    for (int i = 0; i < 4; ++i) {
      __syncthreads();
      const int lrow0 = wm * 16 + l4 * 4;
#pragma unroll
      for (int jn = 0; jn < 4; ++jn) {
        const int col = wn * 64 + jn * 16 + l15;
#pragma unroll
        for (int r = 0; r < 4; ++r) rep[(lrow0 + r) * 132 + col] = acc[i][jn][r];
      }
      __syncthreads();
#pragma unroll
      for (int pp = 0; pp < 4; ++pp) {
        const int lrow = pp * 8 + (t >> 5);
        const int grow = tm * 128 + (lrow >> 4) * 64 + i * 16 + (lrow & 15);
        const int gcol = tn * 128 + (t & 31) * 4;
        *(float4*)&((float*)Cv)[(long)z * sC + (long)grow * ldc + gcol] =
            *(const float4*)&rep[lrow * 132 + (t & 31) * 4];
      }
    }
  }
}

// --------------------------------- driver ----------------------------------

extern "C" void kernel_launch(void* const* d_in, const int* in_sizes, int n_in,
                              void* d_out, int out_size, void* d_ws,
                              size_t ws_size, hipStream_t stream) {
  const float* query = (const float*)d_in[0];
  const float* value = (const float*)d_in[1];
  const float* Wq = (const float*)d_in[2];
  const float* bq = (const float*)d_in[3];
  const float* Wk = (const float*)d_in[4];
  const float* bk = (const float*)d_in[5];
  const float* Wv = (const float*)d_in[6];
  const float* bv = (const float*)d_in[7];
  const float* Wr = (const float*)d_in[8];
  const float* br = (const float*)d_in[9];
  float* out = (float*)d_out;

  if (ws_size < 169000000ull) {
    sentinel<<<1, 1, 0, stream>>>(out);
    return;
  }

  char* p = (char*)d_ws;
  auto alloc = [&](size_t bytes) {
    char* r = p;
    p += (bytes + 255) & ~(size_t)255;
    return r;
  };
  const size_t QV = 16777216ull;  // B*S*D elements
  const size_t WW = 1048576ull;   // 1024*1024 elements
  char* bufA = alloc(QV * 2);  // q16 -> Khat
  char* bufB = alloc(QV * 2);  // v16 -> probs z-even (32MB)
  char* bufC = alloc(QV * 2);  // Qhat
  char* bufD = alloc(QV * 2);  // VT
  f16* q16 = (f16*)bufA;
  f16* Khat = (f16*)bufA;
  f16* v16 = (f16*)bufB;
  f16* probs0 = (f16*)bufB;  // pair slot 0; slot 1 = weights region (+96MB)
  f16* Qhat = (f16*)bufC;
  f16* VT = (f16*)bufD;
  // weights region: 32 MB from Wq_h onward is reused as probs slot 1
  f16* Wq_h = (f16*)alloc(WW * 2);
  f16* Wq_l = (f16*)alloc(WW * 2);
  f16* Wk_h = (f16*)alloc(WW * 2);
  f16* Wk_l = (f16*)alloc(WW * 2);
  f16* Wr_h = (f16*)alloc(WW * 2);
  f16* Wr_l = (f16*)alloc(WW * 2);
  f16* Wv16 = (f16*)alloc(WW * 2);
  f16* WrT_h = (f16*)alloc(WW * 2);
  f16* WrT_l = (f16*)alloc(WW * 2);
  f16* WvT = (f16*)alloc(WW * 2);
  float* Wtmp32 = (float*)alloc(WW * 8);  // [2][1024][1024] f32
  f16* WqrT_h = (f16*)alloc(WW * 2);
  f16* WqrT_l = (f16*)alloc(WW * 2);
  f16* WkrT_h = (f16*)alloc(WW * 2);
  f16* WkrT_l = (f16*)alloc(WW * 2);
  float* brq = (float*)alloc(1024 * 4);
  float* brk = (float*)alloc(1024 * 4);
  float* m_loc = (float*)alloc(2 * 32 * 4096 * 4);  // [z2][tn][row]
  float* l_loc = (float*)alloc(2 * 32 * 4096 * 4);
  f16* scl = (f16*)alloc(2 * 32 * 4096 * 2);  // [z2][tile][row] = alpha/l
  const long PSTRIDE = 50331648;  // f16 elems between probs slot 0 and slot 1

  // fp32 -> fp16 conversions (split for W matrices feeding Wqr/Wkr)
  f2h<<<16384, 256, 0, stream>>>(query, q16, 4194304);
  f2h<<<16384, 256, 0, stream>>>(value, v16, 4194304);
  f2h_split<<<1024, 256, 0, stream>>>(Wq, Wq_h, Wq_l, 262144);
  f2h_split<<<1024, 256, 0, stream>>>(Wk, Wk_h, Wk_l, 262144);
  f2h_split<<<1024, 256, 0, stream>>>(Wr, Wr_h, Wr_l, 262144);
  f2h<<<1024, 256, 0, stream>>>(Wv, Wv16, 262144);
  tr_h<<<dim3(32, 32), dim3(32, 32), 0, stream>>>(Wr_h, WrT_h, 1024, 1024);
  tr_h<<<dim3(32, 32), dim3(32, 32), 0, stream>>>(Wr_l, WrT_l, 1024, 1024);
  tr_h<<<dim3(32, 32), dim3(32, 32), 0, stream>>>(Wv16, WvT, 1024, 1024);
  bias_fold<<<4, 256, 0, stream>>>(br, bq, Wr, brq);
  bias_fold<<<4, 256, 0, stream>>>(br, bk, Wr, brk);

  // W{q,k}rT = Wr^T @ W{q,k}^T in ~fp32 (Ah@Bh + Ah@Bl + Al@Bh), one z=2 pass
  gemm_bt<5, true, true><<<dim3(8, 8, 2), 256, 0, stream>>>(
      WrT_h, WrT_l, Wq_h, Wq_l, Wtmp32, nullptr, nullptr, nullptr, nullptr, 0,
      1024, 1024, 1024, 1024, 1024, 1024, 0, 2097152, 1048576, 0);
  f2h_split<<<1024, 256, 0, stream>>>(Wtmp32, WqrT_h, WqrT_l, 262144);
  f2h_split<<<1024, 256, 0, stream>>>(Wtmp32 + 1048576, WkrT_h, WkrT_l, 262144);

  // Qhat = cos(query @ Wqr + brq)   [bufC]  (B = hi + lo, fused dual-B)
  gemm_bt<1, false, true><<<dim3(8, 128, 1), 256, 0, stream>>>(
      q16, nullptr, WqrT_h, WqrT_l, Qhat, brq, nullptr, nullptr, nullptr, 0,
      16384, 1024, 1024, 1024, 1024, 1024, 0, 0, 0, 0);
  // Khat = cos(value @ Wkr + brk)   [bufA — q16 dead from here]
  gemm_bt<1, false, true><<<dim3(8, 128, 1), 256, 0, stream>>>(
      v16, nullptr, WkrT_h, WkrT_l, Khat, brk, nullptr, nullptr, nullptr, 0,
      16384, 1024, 1024, 1024, 1024, 1024, 0, 0, 0, 0);
  // VT[u][s] = (value @ Wv + bv)^T = Wv^T @ value^T  (row bias bv)  [bufD]
  gemm_bt<2, false, false><<<dim3(128, 8, 1), 256, 0, stream>>>(
      WvT, nullptr, v16, nullptr, VT, bv, nullptr, nullptr, nullptr, 0, 1024,
      16384, 1024, 1024, 1024, 16384, 0, 0, 0, 0);

  // per batch-pair: probs = exp(S - m_tile) + stats; merge; PV (scale folded)
  for (int zb = 0; zb < NB; zb += 2) {
    gemm_bt<6, false, false><<<dim3(32, 32, 2), 256, 0, stream>>>(
        Qhat + (long)zb * 4194304, nullptr, Khat + (long)zb * 4194304, nullptr,
        probs0, nullptr, m_loc, l_loc, nullptr, 0, 4096, 4096, 1024, 1024,
        1024, 4096, 4194304, 4194304, PSTRIDE, 0);
    merge_pair<<<32, 256, 0, stream>>>(m_loc, l_loc, scl);
    gemm_bt<7, false, false><<<dim3(8, 32, 2), 256, 0, stream>>>(
        probs0, nullptr, VT + (long)zb * 4096, nullptr, out + (long)zb * 4194304,
        nullptr, nullptr, nullptr, scl, 131072, 4096, 1024, 4096, 4096, 16384,
        1024, PSTRIDE, 4096, 4194304, 0);
  }
}

// Round 7
// 758.122 us; speedup vs baseline: 5.3243x; 1.1864x over previous
//
#include <hip/hip_runtime.h>
#include <hip/hip_bf16.h>
#include <hip/hip_fp16.h>
#include <cstdint>

// ---------------------------------------------------------------------------
// LinearAttention (random-feature cos kernel + softmax attention), MI355X.
// out = softmax(cos(q@Wq@Wr + br) @ cos(v@Wk@Wr + br)^T) @ (v@Wv + bv)
// B=4, S=4096, D=U=F=1024.  All heavy math in fp16 MFMA with fp32 accum.
// GEMM: 128x128 tile, double-buffered LDS, 2-phase pipeline with counted
// vmcnt (T3/T4 minimum recipe).  Softmax: tile-local max in QK^T epilogue
// (EPI=6) + alpha/l folded into PV A-fragments (EPI=7), scales LDS-staged.
// ---------------------------------------------------------------------------

typedef _Float16 f16;
typedef _Float16 f16x8 __attribute__((ext_vector_type(8)));
typedef _Float16 f16x4 __attribute__((ext_vector_type(4)));
typedef float f32x4 __attribute__((ext_vector_type(4)));

typedef __attribute__((address_space(1))) unsigned int uas1;
typedef __attribute__((address_space(3))) unsigned int uas3;

#define NB 4
#define SEQ 4096
#define DIM 1024

// async 16B/lane global->LDS. LDS dest must be wave-uniform base (+lane*16).
__device__ __forceinline__ void async_copy16(void* lds, const void* g) {
  __builtin_amdgcn_global_load_lds((uas1*)(uintptr_t)g, (uas3*)(uintptr_t)lds,
                                   16, 0, 0);
}

// ----------------------------- small kernels ------------------------------

__global__ __launch_bounds__(256) void f2h(const float* __restrict__ in,
                                           f16* __restrict__ out, int n4) {
  int i = blockIdx.x * 256 + threadIdx.x;
  if (i < n4) {
    float4 v = ((const float4*)in)[i];
    f16x4 h = {(f16)v.x, (f16)v.y, (f16)v.z, (f16)v.w};
    ((f16x4*)out)[i] = h;
  }
}

__global__ __launch_bounds__(256) void f2h_split(const float* __restrict__ in,
                                                 f16* __restrict__ hi,
                                                 f16* __restrict__ lo, int n4) {
  int i = blockIdx.x * 256 + threadIdx.x;
  if (i < n4) {
    float4 v = ((const float4*)in)[i];
    f16 h0 = (f16)v.x, h1 = (f16)v.y, h2 = (f16)v.z, h3 = (f16)v.w;
    f16x4 hv = {h0, h1, h2, h3};
    f16x4 lv = {(f16)(v.x - (float)h0), (f16)(v.y - (float)h1),
                (f16)(v.z - (float)h2), (f16)(v.w - (float)h3)};
    ((f16x4*)hi)[i] = hv;
    ((f16x4*)lo)[i] = lv;
  }
}

__global__ void tr_h(const f16* __restrict__ in, f16* __restrict__ out, int R,
                     int C) {
  __shared__ f16 tile[32][33];
  int c0 = blockIdx.x * 32, r0 = blockIdx.y * 32;
  tile[threadIdx.y][threadIdx.x] =
      in[(long)(r0 + threadIdx.y) * C + c0 + threadIdx.x];
  __syncthreads();
  out[(long)(c0 + threadIdx.y) * R + r0 + threadIdx.x] =
      tile[threadIdx.x][threadIdx.y];
}

// bias_eff[f] = br[f] + sum_u bvec[u] * Wr[u][f]   (fp32 exact)
__global__ __launch_bounds__(256) void bias_fold(const float* __restrict__ br,
                                                 const float* __restrict__ bvec,
                                                 const float* __restrict__ Wr,
                                                 float* __restrict__ outb) {
  int f = blockIdx.x * 256 + threadIdx.x;
  float s = br[f];
  for (int u = 0; u < DIM; ++u) s = fmaf(bvec[u], Wr[(long)u * DIM + f], s);
  outb[f] = s;
}

// per (z2,row): m = max_t m_t; l = sum_t l_t exp(m_t-m);
// scl[t][row] = exp(m_t-m)/l  (f16)
__global__ __launch_bounds__(256) void merge_pair(const float* __restrict__ ml,
                                                  const float* __restrict__ ll,
                                                  f16* __restrict__ scl) {
  int i = blockIdx.x * 256 + threadIdx.x;  // 0..8191 = z2*4096 + row
  int z2 = i >> 12, row = i & 4095;
  const float* m = ml + z2 * 131072 + row;
  const float* lp = ll + z2 * 131072 + row;
  float a[32];
  float mg = -1e30f;
#pragma unroll 32
  for (int t = 0; t < 32; ++t) mg = fmaxf(mg, m[t * 4096]);
  float l = 0.f;
#pragma unroll 32
  for (int t = 0; t < 32; ++t) {
    a[t] = __expf(m[t * 4096] - mg);
    l += lp[t * 4096] * a[t];
  }
  float li = 1.0f / l;
#pragma unroll 32
  for (int t = 0; t < 32; ++t)
    scl[z2 * 131072 + t * 4096 + row] = (f16)(a[t] * li);
}

__global__ void sentinel(float* out) { out[0] = 12345.0f; }

// ------------------------------- main GEMM --------------------------------
// C[M,N] = epilogue( A@B^T [+ A@Bl^T if DB] [+ Al@B^T if DA] )
// B stored row-major [N,K].  128x128 tile, 4 waves, 4x4 16x16x32 frags/wave.
// Double-buffered LDS, 2-phase pipeline, counted vmcnt (never 0 in loop).
// EPI: 1 f16 __cosf(v+aux[col]) | 2 f16 v+aux[row] | 5 f32 plain
//      6 f16 exp(v - rowmax_tile) + write mout/lout per (z,tn,row)
//      7 f32 plain, A-fragments scaled by ascl[ktile][arow] (LDS-staged)
template <int EPI, bool DA, bool DB, int BK>
__global__ __launch_bounds__(256) void gemm_bt(
    const f16* __restrict__ Ah, const f16* __restrict__ Al,
    const f16* __restrict__ Bh, const f16* __restrict__ Bl,
    void* __restrict__ Cv, const float* __restrict__ aux,
    float* __restrict__ mout, float* __restrict__ lout,
    const f16* __restrict__ ascl, long sAscl, int M, int N, int K, int lda,
    int ldb, int ldc, long sC, long sA, long sB, int sAux) {
  constexpr int NSTAGE = 2 + (DA ? 1 : 0) + (DB ? 1 : 0);
  constexpr int TILE = 128 * BK * 2;  // bytes per operand tile
  constexpr int CPR = BK / 8;         // 16B chunks per row
  constexpr int CH = 128 * CPR;       // chunks per operand tile
  constexpr int NL = NSTAGE * BK / 16;  // per-thread vmem issues per tile
  static_assert(NL == 6 || NL == 8, "vmcnt literal");
  constexpr int SCLB = (EPI == 7) ? 8192 : 0;
  __shared__ __align__(16) char smem[2 * NSTAGE * TILE + SCLB];
  __shared__ float red6[EPI == 6 ? 2 : 1][EPI == 6 ? 128 : 1];

  const int z = blockIdx.z;
  const int tn = blockIdx.x, tm = blockIdx.y;
  const int t = threadIdx.x, w = t >> 6, l = t & 63;
  const int l4 = l >> 4, l15 = l & 15;
  const int wm = w & 1, wn = w >> 1;
  f32x4 acc[4][4] = {};

  const f16* Az = Ah + (long)z * sA;
  const f16* Bz = Bh + (long)z * sB;
  const f16* Alz = nullptr;
  const f16* Blz = nullptr;
  if constexpr (DA) Alz = Al + (long)z * sA;
  if constexpr (DB) Blz = Bl + (long)z * sB;
  f16* sclLds = (f16*)(smem + 2 * NSTAGE * TILE);

  auto swz = [](int r, int p) -> int {
    if constexpr (BK == 64) return p ^ (r & 7);
    else return p ^ ((r >> 1) & 3);
  };

  auto STAGE = [&](int buf, int kk) {
    char* base = smem + buf * (NSTAGE * TILE);
#pragma unroll
    for (int j = 0; j < CH / 256; ++j) {
      const int cb = j * 256 + w * 64;  // wave-uniform chunk base
      const int c = cb + l;
      const int r = c / CPR, pp = c % CPR;
      const int sc = swz(r, pp);
      const long ra = (long)(tm * 128 + r) * lda + kk + sc * 8;
      const long rb = (long)(tn * 128 + r) * ldb + kk + sc * 8;
      async_copy16(base + cb * 16, Az + ra);
      async_copy16(base + TILE + cb * 16, Bz + rb);
      if constexpr (DA) async_copy16(base + 2 * TILE + cb * 16, Alz + ra);
      if constexpr (DB)
        async_copy16(base + (2 + (DA ? 1 : 0)) * TILE + cb * 16, Blz + rb);
    }
  };

  // ---- prologue: stage tile 0 (+ scl table for EPI 7), drain, barrier ----
  STAGE(0, 0);
  if constexpr (EPI == 7) {
    const f16* asclz = ascl + (long)z * sAscl;
    // 32 k-tiles x 128 rows f16 -> 512 chunks; LDS idx c*8 = tile*128 + row
#pragma unroll
    for (int j = 0; j < 2; ++j) {
      const int cb = j * 256 + w * 64;
      const int c = cb + l;
      async_copy16(sclLds + cb * 8,
                   asclz + (long)(c >> 4) * M + tm * 128 + (c & 15) * 8);
    }
  }
  asm volatile("s_waitcnt vmcnt(0)" ::: "memory");
  __syncthreads();

  const int nt = K / BK;
  int cur = 0;
  for (int tt = 0; tt < nt; ++tt) {
    const int kk = tt * BK;
    if (tt + 1 < nt) {
      STAGE(cur ^ 1, kk + BK);
      if constexpr (NL == 6)
        asm volatile("s_waitcnt vmcnt(6)" ::: "memory");
      else
        asm volatile("s_waitcnt vmcnt(8)" ::: "memory");
    } else {
      asm volatile("s_waitcnt vmcnt(0)" ::: "memory");
    }
    __syncthreads();

    const f16* As = (const f16*)(smem + cur * (NSTAGE * TILE));
    const f16* Bs = As + TILE / 2;
    const f16* Als = Bs + TILE / 2;
    const f16* Bls = Als + (DA ? TILE / 2 : 0);

    f16 sA4[4];
    if constexpr (EPI == 7) {
      const int tile = kk >> 7;
#pragma unroll
      for (int i = 0; i < 4; ++i)
        sA4[i] = sclLds[tile * 128 + wm * 64 + i * 16 + l15];
    }

#pragma unroll
    for (int ks = 0; ks < BK / 32; ++ks) {
      f16x8 af[4], bf[4];
#pragma unroll
      for (int i = 0; i < 4; ++i) {
        const int ra = wm * 64 + i * 16 + l15;
        const int rb = wn * 64 + i * 16 + l15;
        af[i] = *(const f16x8*)&As[ra * BK + swz(ra, ks * 4 + l4) * 8];
        bf[i] = *(const f16x8*)&Bs[rb * BK + swz(rb, ks * 4 + l4) * 8];
      }
      if constexpr (EPI == 7) {
#pragma unroll
        for (int i = 0; i < 4; ++i) af[i] = af[i] * sA4[i];
      }
#pragma unroll
      for (int i = 0; i < 4; ++i)
#pragma unroll
        for (int jn = 0; jn < 4; ++jn)
          acc[i][jn] = __builtin_amdgcn_mfma_f32_16x16x32_f16(af[i], bf[jn],
                                                              acc[i][jn], 0, 0, 0);
      if constexpr (DB) {
        f16x8 bl[4];
#pragma unroll
        for (int i = 0; i < 4; ++i) {
          const int rb = wn * 64 + i * 16 + l15;
          bl[i] = *(const f16x8*)&Bls[rb * BK + swz(rb, ks * 4 + l4) * 8];
        }
#pragma unroll
        for (int i = 0; i < 4; ++i)
#pragma unroll
          for (int jn = 0; jn < 4; ++jn)
            acc[i][jn] = __builtin_amdgcn_mfma_f32_16x16x32_f16(
                af[i], bl[jn], acc[i][jn], 0, 0, 0);
      }
      if constexpr (DA) {
        f16x8 al[4];
#pragma unroll
        for (int i = 0; i < 4; ++i) {
          const int ra = wm * 64 + i * 16 + l15;
          al[i] = *(const f16x8*)&Als[ra * BK + swz(ra, ks * 4 + l4) * 8];
        }
#pragma unroll
        for (int i = 0; i < 4; ++i)
#pragma unroll
          for (int jn = 0; jn < 4; ++jn)
            acc[i][jn] = __builtin_amdgcn_mfma_f32_16x16x32_f16(
                al[i], bf[jn], acc[i][jn], 0, 0, 0);
      }
    }
    __syncthreads();
    cur ^= 1;
  }

  if constexpr (EPI == 6) {
    // ---- tile-local softmax: per-row max over this 128-col tile ----
    float mrow[16];
#pragma unroll
    for (int i = 0; i < 4; ++i)
#pragma unroll
      for (int r = 0; r < 4; ++r) {
        float v = fmaxf(fmaxf(acc[i][0][r], acc[i][1][r]),
                        fmaxf(acc[i][2][r], acc[i][3][r]));
        v = fmaxf(v, __shfl_xor(v, 1));
        v = fmaxf(v, __shfl_xor(v, 2));
        v = fmaxf(v, __shfl_xor(v, 4));
        v = fmaxf(v, __shfl_xor(v, 8));
        if (l15 == 0) red6[wn][wm * 64 + i * 16 + l4 * 4 + r] = v;
      }
    __syncthreads();
#pragma unroll
    for (int i = 0; i < 4; ++i)
#pragma unroll
      for (int r = 0; r < 4; ++r) {
        const int rin = wm * 64 + i * 16 + l4 * 4 + r;
        mrow[i * 4 + r] = fmaxf(red6[0][rin], red6[1][rin]);
      }
    __syncthreads();
#pragma unroll
    for (int i = 0; i < 4; ++i)
#pragma unroll
      for (int r = 0; r < 4; ++r) {
        const float mn = mrow[i * 4 + r];
        float s = 0.f;
#pragma unroll
        for (int jn = 0; jn < 4; ++jn) {
          float e = __expf(acc[i][jn][r] - mn);
          acc[i][jn][r] = e;
          s += e;
        }
        s += __shfl_xor(s, 1);
        s += __shfl_xor(s, 2);
        s += __shfl_xor(s, 4);
        s += __shfl_xor(s, 8);
        if (l15 == 0) red6[wn][wm * 64 + i * 16 + l4 * 4 + r] = s;
      }
    __syncthreads();
    if (wn == 0 && l15 == 0) {
#pragma unroll
      for (int i = 0; i < 4; ++i)
#pragma unroll
        for (int r = 0; r < 4; ++r) {
          const int rin = wm * 64 + i * 16 + l4 * 4 + r;
          const int gidx = z * 131072 + tn * 4096 + tm * 128 + rin;
          mout[gidx] = mrow[i * 4 + r];
          lout[gidx] = red6[0][rin] + red6[1][rin];
        }
    }
  }

  const float* auxp = aux + (long)z * sAux;

  if constexpr (EPI == 1 || EPI == 2 || EPI == 6) {
    // ---- f16 output via LDS repack: [64][136] per half ----
    f16* rep = (f16*)smem;
#pragma unroll
    for (int hh = 0; hh < 2; ++hh) {
      __syncthreads();
#pragma unroll
      for (int ii = 0; ii < 2; ++ii) {
        const int i = hh * 2 + ii;
        const int lrow0 = wm * 32 + ii * 16 + l4 * 4;
#pragma unroll
        for (int jn = 0; jn < 4; ++jn) {
          const int col = wn * 64 + jn * 16 + l15;
#pragma unroll
          for (int r = 0; r < 4; ++r) {
            float v = acc[i][jn][r];
            f16 hv;
            if constexpr (EPI == 1)
              hv = (f16)__cosf(v + auxp[tn * 128 + col]);
            else if constexpr (EPI == 2)
              hv = (f16)(v + auxp[tm * 128 + wm * 64 + i * 16 + l4 * 4 + r]);
            else
              hv = (f16)v;
            rep[(lrow0 + r) * 136 + col] = hv;
          }
        }
      }
      __syncthreads();
#pragma unroll
      for (int pp = 0; pp < 4; ++pp) {
        const int lrow = pp * 16 + (t >> 4);
        const int grow = tm * 128 + (lrow >> 5) * 64 + hh * 32 + (lrow & 31);
        const int gcol = tn * 128 + (t & 15) * 8;
        *(f16x8*)&((f16*)Cv)[(long)z * sC + (long)grow * ldc + gcol] =
            *(const f16x8*)&rep[lrow * 136 + (t & 15) * 8];
      }
    }
  } else {
    // ---- f32 output via LDS repack: [32][132] per i-group ----
    float* rep = (float*)smem;
#pragma unroll
    for (int i = 0; i < 4; ++i) {
      __syncthreads();
      const int lrow0 = wm * 16 + l4 * 4;
#pragma unroll
      for (int jn = 0; jn < 4; ++jn) {
        const int col = wn * 64 + jn * 16 + l15;
#pragma unroll
        for (int r = 0; r < 4; ++r) rep[(lrow0 + r) * 132 + col] = acc[i][jn][r];
      }
      __syncthreads();
#pragma unroll
      for (int pp = 0; pp < 4; ++pp) {
        const int lrow = pp * 8 + (t >> 5);
        const int grow = tm * 128 + (lrow >> 4) * 64 + i * 16 + (lrow & 15);
        const int gcol = tn * 128 + (t & 31) * 4;
        *(float4*)&((float*)Cv)[(long)z * sC + (long)grow * ldc + gcol] =
            *(const float4*)&rep[lrow * 132 + (t & 31) * 4];
      }
    }
  }
}

// --------------------------------- driver ----------------------------------

extern "C" void kernel_launch(void* const* d_in, const int* in_sizes, int n_in,
                              void* d_out, int out_size, void* d_ws,
                              size_t ws_size, hipStream_t stream) {
  const float* query = (const float*)d_in[0];
  const float* value = (const float*)d_in[1];
  const float* Wq = (const float*)d_in[2];
  const float* bq = (const float*)d_in[3];
  const float* Wk = (const float*)d_in[4];
  const float* bk = (const float*)d_in[5];
  const float* Wv = (const float*)d_in[6];
  const float* bv = (const float*)d_in[7];
  const float* Wr = (const float*)d_in[8];
  const float* br = (const float*)d_in[9];
  float* out = (float*)d_out;

  if (ws_size < 169000000ull) {
    sentinel<<<1, 1, 0, stream>>>(out);
    return;
  }

  char* p = (char*)d_ws;
  auto alloc = [&](size_t bytes) {
    char* r = p;
    p += (bytes + 255) & ~(size_t)255;
    return r;
  };
  const size_t QV = 16777216ull;  // B*S*D elements
  const size_t WW = 1048576ull;   // 1024*1024 elements
  char* bufA = alloc(QV * 2);  // q16 -> Khat
  char* bufB = alloc(QV * 2);  // v16 -> probs z-even (32MB)
  char* bufC = alloc(QV * 2);  // Qhat
  char* bufD = alloc(QV * 2);  // VT
  f16* q16 = (f16*)bufA;
  f16* Khat = (f16*)bufA;
  f16* v16 = (f16*)bufB;
  f16* probs0 = (f16*)bufB;  // pair slot 0; slot 1 = weights region (+96MB)
  f16* Qhat = (f16*)bufC;
  f16* VT = (f16*)bufD;
  // weights region: 32 MB from Wq_h onward is reused as probs slot 1
  f16* Wq_h = (f16*)alloc(WW * 2);
  f16* Wq_l = (f16*)alloc(WW * 2);
  f16* Wk_h = (f16*)alloc(WW * 2);
  f16* Wk_l = (f16*)alloc(WW * 2);
  f16* Wr_h = (f16*)alloc(WW * 2);
  f16* Wr_l = (f16*)alloc(WW * 2);
  f16* Wv16 = (f16*)alloc(WW * 2);
  f16* WrT_h = (f16*)alloc(WW * 2);
  f16* WrT_l = (f16*)alloc(WW * 2);
  f16* WvT = (f16*)alloc(WW * 2);
  float* Wtmp32 = (float*)alloc(WW * 8);  // [2][1024][1024] f32
  f16* WqrT_h = (f16*)alloc(WW * 2);
  f16* WqrT_l = (f16*)alloc(WW * 2);
  f16* WkrT_h = (f16*)alloc(WW * 2);
  f16* WkrT_l = (f16*)alloc(WW * 2);
  float* brq = (float*)alloc(1024 * 4);
  float* brk = (float*)alloc(1024 * 4);
  float* m_loc = (float*)alloc(2 * 32 * 4096 * 4);  // [z2][tn][row]
  float* l_loc = (float*)alloc(2 * 32 * 4096 * 4);
  f16* scl = (f16*)alloc(2 * 32 * 4096 * 2);  // [z2][tile][row] = alpha/l
  const long PSTRIDE = 50331648;  // f16 elems between probs slot 0 and slot 1

  // fp32 -> fp16 conversions (split for W matrices feeding Wqr/Wkr)
  f2h<<<16384, 256, 0, stream>>>(query, q16, 4194304);
  f2h<<<16384, 256, 0, stream>>>(value, v16, 4194304);
  f2h_split<<<1024, 256, 0, stream>>>(Wq, Wq_h, Wq_l, 262144);
  f2h_split<<<1024, 256, 0, stream>>>(Wk, Wk_h, Wk_l, 262144);
  f2h_split<<<1024, 256, 0, stream>>>(Wr, Wr_h, Wr_l, 262144);
  f2h<<<1024, 256, 0, stream>>>(Wv, Wv16, 262144);
  tr_h<<<dim3(32, 32), dim3(32, 32), 0, stream>>>(Wr_h, WrT_h, 1024, 1024);
  tr_h<<<dim3(32, 32), dim3(32, 32), 0, stream>>>(Wr_l, WrT_l, 1024, 1024);
  tr_h<<<dim3(32, 32), dim3(32, 32), 0, stream>>>(Wv16, WvT, 1024, 1024);
  bias_fold<<<4, 256, 0, stream>>>(br, bq, Wr, brq);
  bias_fold<<<4, 256, 0, stream>>>(br, bk, Wr, brk);

  // W{q,k}rT = Wr^T @ W{q,k}^T in ~fp32 (Ah@Bh + Ah@Bl + Al@Bh), one z=2 pass
  gemm_bt<5, true, true, 32><<<dim3(8, 8, 2), 256, 0, stream>>>(
      WrT_h, WrT_l, Wq_h, Wq_l, Wtmp32, nullptr, nullptr, nullptr, nullptr, 0,
      1024, 1024, 1024, 1024, 1024, 1024, 1048576, 0, 2097152, 0);
  f2h_split<<<1024, 256, 0, stream>>>(Wtmp32, WqrT_h, WqrT_l, 262144);
  f2h_split<<<1024, 256, 0, stream>>>(Wtmp32 + 1048576, WkrT_h, WkrT_l, 262144);

  // Qhat = cos(query @ Wqr + brq)   [bufC]  (B = hi + lo, fused dual-B)
  gemm_bt<1, false, true, 32><<<dim3(8, 128, 1), 256, 0, stream>>>(
      q16, nullptr, WqrT_h, WqrT_l, Qhat, brq, nullptr, nullptr, nullptr, 0,
      16384, 1024, 1024, 1024, 1024, 1024, 0, 0, 0, 0);
  // Khat = cos(value @ Wkr + brk)   [bufA — q16 dead from here]
  gemm_bt<1, false, true, 32><<<dim3(8, 128, 1), 256, 0, stream>>>(
      v16, nullptr, WkrT_h, WkrT_l, Khat, brk, nullptr, nullptr, nullptr, 0,
      16384, 1024, 1024, 1024, 1024, 1024, 0, 0, 0, 0);
  // VT[u][s] = (value @ Wv + bv)^T = Wv^T @ value^T  (row bias bv)  [bufD]
  gemm_bt<2, false, false, 64><<<dim3(128, 8, 1), 256, 0, stream>>>(
      WvT, nullptr, v16, nullptr, VT, bv, nullptr, nullptr, nullptr, 0, 1024,
      16384, 1024, 1024, 1024, 16384, 0, 0, 0, 0);

  // per batch-pair: probs = exp(S - m_tile) + stats; merge; PV (scale folded)
  for (int zb = 0; zb < NB; zb += 2) {
    gemm_bt<6, false, false, 64><<<dim3(32, 32, 2), 256, 0, stream>>>(
        Qhat + (long)zb * 4194304, nullptr, Khat + (long)zb * 4194304, nullptr,
        probs0, nullptr, m_loc, l_loc, nullptr, 0, 4096, 4096, 1024, 1024,
        1024, 4096, PSTRIDE, 4194304, 4194304, 0);
    merge_pair<<<32, 256, 0, stream>>>(m_loc, l_loc, scl);
    gemm_bt<7, false, false, 64><<<dim3(8, 32, 2), 256, 0, stream>>>(
        probs0, nullptr, VT + (long)zb * 4096, nullptr, out + (long)zb * 4194304,
        nullptr, nullptr, nullptr, scl, 131072, 4096, 1024, 4096, 4096, 16384,
        1024, 4194304, PSTRIDE, 4096, 0);
  }
}